// Round 1
// baseline (5064.805 us; speedup 1.0000x reference)
//
#include <hip/hip_runtime.h>
#include <math.h>

// ---------------- weight transpose: (COUT,CIN,3,3) -> (CIN*9, COUTP) ----------------
__global__ void wtrans_kernel(const float* __restrict__ src, float* __restrict__ dst,
                              int COUT, int CIN, int COUTP,
                              int per_scale_src, int per_scale_dst) {
  const int s = blockIdx.z;
  src += (size_t)s * per_scale_src;
  dst += (size_t)s * per_scale_dst;
  const int total = COUT * CIN * 9;
  for (int idx = blockIdx.x * blockDim.x + threadIdx.x; idx < total;
       idx += gridDim.x * blockDim.x) {
    int t  = idx % 9;
    int ic = (idx / 9) % CIN;
    int oc = idx / (9 * CIN);
    dst[(ic * 9 + t) * COUTP + oc] = src[idx];
  }
}

// ---------------- nearest downsample (C=1), ri = i*r ----------------
__global__ void downsample_kernel(const float* __restrict__ in, float* __restrict__ out,
                                  int Hs, int Ws, int r, int W) {
  const float* ip = in + (size_t)blockIdx.z * W * W;
  float* op = out + (size_t)blockIdx.z * Hs * Ws;
  int idx = blockIdx.x * blockDim.x + threadIdx.x;
  if (idx < Hs * Ws) {
    int rr = idx / Ws, cc = idx % Ws;
    op[idx] = ip[(size_t)(rr * r) * W + cc * r];
  }
}

// ---------------- generic 3x3 SAME conv, NHWC, wave=64 oc-lanes ----------------
// Block: 256 thr = 4 waves. Block tile 16 rows x 8 cols; wave w owns rows [4w,4w+4).
// LDS slab: input tile+halo (18 x 10 used, stride 12 for float4-aligned rows).
// Weights pre-transposed: wT[(ic*9+t)*COUTP + oc] -> coalesced per-ic lane loads.
template <int CIN, int COUT, int COUTP, bool RELU>
__global__ __launch_bounds__(256)
void conv3x3_kernel(const float* __restrict__ in, const float* __restrict__ wT,
                    const float* __restrict__ bias, float* __restrict__ out,
                    int H, int W) {
  __shared__ __align__(16) float slab[CIN * 18 * 12];
  const int tid = threadIdx.x;
  const int gr0 = blockIdx.y * 16;
  const int gc0 = blockIdx.x * 8;
  // stage input tile (zero-padded at image borders); coalesced: ic fastest
  for (int idx = tid; idx < CIN * 18 * 10; idx += 256) {
    int ic = idx % CIN;
    int px = idx / CIN;
    int r = px / 10, c = px % 10;
    int gr = gr0 - 1 + r, gc = gc0 - 1 + c;
    float v = 0.f;
    if (gr >= 0 && gr < H && gc >= 0 && gc < W)
      v = in[((size_t)gr * W + gc) * CIN + ic];
    slab[(ic * 18 + r) * 12 + c] = v;
  }
  __syncthreads();
  const int lane = tid & 63;
  const int wr0 = (tid >> 6) * 4;
  for (int oc0 = 0; oc0 < COUT; oc0 += 64) {
    const int oc = oc0 + lane;
    const bool active = oc < COUT;
    const float bval = active ? bias[oc] : 0.f;
    float acc[4][8];
#pragma unroll
    for (int i = 0; i < 4; ++i)
#pragma unroll
      for (int j = 0; j < 8; ++j) acc[i][j] = 0.f;
#pragma unroll 1
    for (int ic = 0; ic < CIN; ++ic) {
      float wk[9];
#pragma unroll
      for (int t = 0; t < 9; ++t)
        wk[t] = active ? wT[(size_t)(ic * 9 + t) * COUTP + oc] : 0.f;
#pragma unroll
      for (int s = 0; s < 6; ++s) {
        const float4* row = (const float4*)&slab[(ic * 18 + wr0 + s) * 12];
        float4 A = row[0], B = row[1], C = row[2];
        float xv[10] = {A.x, A.y, A.z, A.w, B.x, B.y, B.z, B.w, C.x, C.y};
#pragma unroll
        for (int ky = 0; ky < 3; ++ky) {
          const int pr = s - ky;  // compile-time after unroll
          if (pr < 0 || pr > 3) continue;
#pragma unroll
          for (int kx = 0; kx < 3; ++kx) {
            const float w = wk[ky * 3 + kx];
#pragma unroll
            for (int cc = 0; cc < 8; ++cc)
              acc[pr][cc] = fmaf(xv[cc + kx], w, acc[pr][cc]);
          }
        }
      }
    }
    if (active) {
#pragma unroll
      for (int pr = 0; pr < 4; ++pr) {
        const int gr = gr0 + wr0 + pr;
#pragma unroll
        for (int cc = 0; cc < 8; ++cc) {
          float v = acc[pr][cc] + bval;
          if (RELU) v = fmaxf(v, 0.f);
          out[((size_t)gr * W + (gc0 + cc)) * COUTP + oc] = v;  // coalesced over oc
        }
      }
    }
  }
}

// ---------------- fused softmax(81) + 9x9 dynamic conv + nearest upsample ----------------
// f: (Hs*Ws, 84) NHWC-padded; s: (Hs,Ws) C=1; writes cat channel `ch` at 512x512.
// No max-subtraction: |f| is O(1), exp is safe in fp32; matches softmax exactly.
template <int RS>
__global__ void softdyn_kernel(const float* __restrict__ f, const float* __restrict__ s,
                               float* __restrict__ cat, int Hs, int Ws, int ch) {
  int idx = blockIdx.x * blockDim.x + threadIdx.x;
  if (idx >= Hs * Ws) return;
  int r = idx / Ws, c = idx % Ws;
  const float4* fp = (const float4*)(f + (size_t)idx * 84);
  float sum = 0.f, y = 0.f;
#pragma unroll
  for (int k4 = 0; k4 < 21; ++k4) {
    float4 v = fp[k4];
    float vals[4] = {v.x, v.y, v.z, v.w};
#pragma unroll
    for (int q = 0; q < 4; ++q) {
      const int k = k4 * 4 + q;
      if (k >= 81) break;
      float e = expf(vals[q]);
      int dy = k / 9, dx = k % 9;
      int rr = r + dy - 4, cc = c + dx - 4;
      float xv = (rr >= 0 && rr < Hs && cc >= 0 && cc < Ws) ? s[(size_t)rr * Ws + cc] : 0.f;
      sum += e;
      y = fmaf(e, xv, y);
    }
  }
  float o = y / sum;
  int R0 = r * RS, C0 = c * RS;
#pragma unroll
  for (int a = 0; a < RS; ++a)
#pragma unroll
    for (int b = 0; b < RS; ++b)
      cat[((size_t)(R0 + a) * 512 + (C0 + b)) * 5 + ch] = o;
}

// ---------------- final 64->1 conv (direct; weights wave-uniform) ----------------
__global__ void conv5_kernel(const float* __restrict__ hid, const float* __restrict__ w,
                             const float* __restrict__ b, float* __restrict__ out,
                             int H, int W) {
  int idx = blockIdx.x * blockDim.x + threadIdx.x;
  if (idx >= H * W) return;
  int r = idx / W, c = idx % W;
  float acc = b[0];
#pragma unroll
  for (int ky = 0; ky < 3; ++ky) {
    int rr = r + ky - 1;
    if (rr < 0 || rr >= H) continue;
#pragma unroll
    for (int kx = 0; kx < 3; ++kx) {
      int cc = c + kx - 1;
      if (cc < 0 || cc >= W) continue;
      const float4* hp = (const float4*)(hid + ((size_t)rr * W + cc) * 64);
      const float* wp = w + (ky * 3 + kx);  // w[ic*9 + t], stride 9 over ic
#pragma unroll
      for (int i = 0; i < 16; ++i) {
        float4 h4 = hp[i];
        acc = fmaf(h4.x, wp[(i * 4 + 0) * 9], acc);
        acc = fmaf(h4.y, wp[(i * 4 + 1) * 9], acc);
        acc = fmaf(h4.z, wp[(i * 4 + 2) * 9], acc);
        acc = fmaf(h4.w, wp[(i * 4 + 3) * 9], acc);
      }
    }
  }
  out[idx] = acc;
}

extern "C" void kernel_launch(void* const* d_in, const int* in_sizes, int n_in,
                              void* d_out, int out_size, void* d_ws, size_t ws_size,
                              hipStream_t stream) {
  (void)in_sizes; (void)n_in; (void)out_size; (void)ws_size;
  const float* x   = (const float*)d_in[0];   // (2,1,512,512)
  const float* g   = (const float*)d_in[1];   // (2,1,512,512)
  const float* fWa = (const float*)d_in[2];   // (5,64,1,3,3)
  const float* fba = (const float*)d_in[3];   // (5,64)
  const float* fWb = (const float*)d_in[4];   // (5,64,64,3,3)
  const float* fbb = (const float*)d_in[5];   // (5,64)
  const float* fWc = (const float*)d_in[6];   // (5,81,64,3,3)
  const float* fbc = (const float*)d_in[7];   // (5,81)
  const float* W2a = (const float*)d_in[8];   // (64,5,3,3)
  const float* b2a = (const float*)d_in[9];   // (64)
  const float* W2b = (const float*)d_in[10];  // (1,64,3,3)
  const float* b2b = (const float*)d_in[11];  // (1)
  float* out = (float*)d_out;
  float* ws = (float*)d_ws;

  // workspace carve (floats); total ~42.1M floats = ~169 MB
  float* wTa = ws;                   // 5 * 1*9*64   = 2880
  float* wTb = wTa + 2880;           // 5 * 64*9*64  = 184320
  float* wTc = wTb + 184320;         // 5 * 64*9*84  = 241920
  float* wTd = wTc + 241920;         // 5*9*64       = 2880
  float* s1  = wTd + 2880;           // 2*256*256    = 131072
  float* s2  = s1 + 131072;          // 2*128*128    = 32768
  float* s3  = s2 + 32768;           // 2*64*64      = 8192
  float* cat = s3 + 8192;            // 2*512*512*5  = 2621440
  float* h2  = cat + 2621440;        // 512*512*64   = 16777216 (1 batch)
  float* h1  = h2 + 16777216;        // 512*512*84 reserved (f aliases h1) = 22020096
  float* fb  = h1;                   // f (conv3 out) overwrites h1 region
  float* hid = h2;                   // hid aliases h2 after scales are done

  // ---- prep: weight transposes ----
  wtrans_kernel<<<dim3(3, 1, 5), 256, 0, stream>>>(fWa, wTa, 64, 1, 64, 576, 576);
  wtrans_kernel<<<dim3(144, 1, 5), 256, 0, stream>>>(fWb, wTb, 64, 64, 64, 36864, 36864);
  wtrans_kernel<<<dim3(183, 1, 5), 256, 0, stream>>>(fWc, wTc, 81, 64, 84, 46656, 48384);
  wtrans_kernel<<<dim3(12, 1, 1), 256, 0, stream>>>(W2a, wTd, 64, 5, 64, 2880, 2880);

  // ---- downsampled scales (both batches) ----
  downsample_kernel<<<dim3(256, 1, 2), 256, 0, stream>>>(x, s1, 256, 256, 2, 512);
  downsample_kernel<<<dim3(64, 1, 2), 256, 0, stream>>>(x, s2, 128, 128, 4, 512);
  downsample_kernel<<<dim3(16, 1, 2), 256, 0, stream>>>(x, s3, 64, 64, 8, 512);

  const int HS_[5] = {512, 256, 128, 64, 512};
  for (int n = 0; n < 2; ++n) {
    const float* sins[5] = {x + (size_t)n * 262144, s1 + (size_t)n * 65536,
                            s2 + (size_t)n * 16384, s3 + (size_t)n * 4096,
                            g + (size_t)n * 262144};
    float* catn = cat + (size_t)n * 1310720;
    for (int i = 0; i < 5; ++i) {
      const int Hs = HS_[i];
      dim3 cgrid(Hs / 8, Hs / 16, 1);
      conv3x3_kernel<1, 64, 64, true><<<cgrid, 256, 0, stream>>>(
          sins[i], wTa + i * 576, fba + i * 64, h1, Hs, Hs);
      conv3x3_kernel<64, 64, 64, true><<<cgrid, 256, 0, stream>>>(
          h1, wTb + i * 36864, fbb + i * 64, h2, Hs, Hs);
      conv3x3_kernel<64, 81, 84, false><<<cgrid, 256, 0, stream>>>(
          h2, wTc + i * 48384, fbc + i * 81, fb, Hs, Hs);
      const int np = (Hs * Hs + 255) / 256;
      switch (i) {
        case 0: softdyn_kernel<1><<<np, 256, 0, stream>>>(fb, sins[i], catn, Hs, Hs, 0); break;
        case 1: softdyn_kernel<2><<<np, 256, 0, stream>>>(fb, sins[i], catn, Hs, Hs, 1); break;
        case 2: softdyn_kernel<4><<<np, 256, 0, stream>>>(fb, sins[i], catn, Hs, Hs, 2); break;
        case 3: softdyn_kernel<8><<<np, 256, 0, stream>>>(fb, sins[i], catn, Hs, Hs, 3); break;
        case 4: softdyn_kernel<1><<<np, 256, 0, stream>>>(fb, sins[i], catn, Hs, Hs, 4); break;
      }
    }
    conv3x3_kernel<5, 64, 64, true><<<dim3(64, 32, 1), 256, 0, stream>>>(
        catn, wTd, b2a, hid, 512, 512);
    conv5_kernel<<<dim3(1024, 1, 1), 256, 0, stream>>>(hid, W2b, b2b,
                                                       out + (size_t)n * 262144, 512, 512);
  }
}

// Round 2
// 1125.016 us; speedup vs baseline: 4.5020x; 4.5020x over previous
//
#include <hip/hip_runtime.h>
#include <math.h>

typedef _Float16 half8 __attribute__((ext_vector_type(8)));
typedef float f32x4 __attribute__((ext_vector_type(4)));

// ---------------- weight transpose: (COUT,CIN,3,3) -> (CIN*9, COUTP), fp32 ----------------
__global__ void wtrans_kernel(const float* __restrict__ src, float* __restrict__ dst,
                              int COUT, int CIN, int COUTP,
                              int per_scale_src, int per_scale_dst) {
  const int s = blockIdx.z;
  src += (size_t)s * per_scale_src;
  dst += (size_t)s * per_scale_dst;
  const int total = COUT * CIN * 9;
  for (int idx = blockIdx.x * blockDim.x + threadIdx.x; idx < total;
       idx += gridDim.x * blockDim.x) {
    int t  = idx % 9;
    int ic = (idx / 9) % CIN;
    int oc = idx / (9 * CIN);
    dst[(ic * 9 + t) * COUTP + oc] = src[idx];
  }
}

// ---------------- weight pack for MFMA: fp32 (COUT,64,3,3) -> fp16 Bpack ----------------
// Bpack[((s*NT + t)*64 + lane)*8 + j] where s=k-step (tap*2+icsel), t=n-tile,
// oc = t*16 + (lane&15), ic = (s&1)*32 + ((lane>>4)&3)*8 + j. Zero-pad oc>=COUT.
__global__ void wpack_kernel(const float* __restrict__ src, _Float16* __restrict__ dst,
                             int COUT, int NT, int per_scale_src, int per_scale_dst) {
  const int sc = blockIdx.z;
  src += (size_t)sc * per_scale_src;
  dst += (size_t)sc * per_scale_dst;
  const int total = 18 * NT * 64 * 8;
  for (int idx = blockIdx.x * blockDim.x + threadIdx.x; idx < total;
       idx += gridDim.x * blockDim.x) {
    int j = idx & 7;
    int lane = (idx >> 3) & 63;
    int rest = idx >> 9;
    int t = rest % NT;
    int s = rest / NT;
    int oc = t * 16 + (lane & 15);
    int tap = s >> 1;
    int ic = (s & 1) * 32 + ((lane >> 4) & 3) * 8 + j;
    float v = (oc < COUT) ? src[((size_t)oc * 64 + ic) * 9 + tap] : 0.f;
    dst[idx] = (_Float16)v;
  }
}

// ---------------- nearest downsample (C=1) ----------------
__global__ void downsample_kernel(const float* __restrict__ in, float* __restrict__ out,
                                  int Hs, int Ws, int r, int W) {
  const float* ip = in + (size_t)blockIdx.z * W * W;
  float* op = out + (size_t)blockIdx.z * Hs * Ws;
  int idx = blockIdx.x * blockDim.x + threadIdx.x;
  if (idx < Hs * Ws) {
    int rr = idx / Ws, cc = idx % Ws;
    op[idx] = ip[(size_t)(rr * r) * W + cc * r];
  }
}

// ---------------- fp32 direct 3x3 conv (used for CIN=1 conv1 and CIN=5 tail) ----------------
template <int CIN, int COUT, int COUTP, bool RELU, typename OutT>
__global__ __launch_bounds__(256)
void conv3x3_kernel(const float* __restrict__ in, const float* __restrict__ wT,
                    const float* __restrict__ bias, OutT* __restrict__ out,
                    int H, int W) {
  __shared__ __align__(16) float slab[CIN * 18 * 12];
  const int tid = threadIdx.x;
  const int gr0 = blockIdx.y * 16;
  const int gc0 = blockIdx.x * 8;
  for (int idx = tid; idx < CIN * 18 * 10; idx += 256) {
    int ic = idx % CIN;
    int px = idx / CIN;
    int r = px / 10, c = px % 10;
    int gr = gr0 - 1 + r, gc = gc0 - 1 + c;
    float v = 0.f;
    if (gr >= 0 && gr < H && gc >= 0 && gc < W)
      v = in[((size_t)gr * W + gc) * CIN + ic];
    slab[(ic * 18 + r) * 12 + c] = v;
  }
  __syncthreads();
  const int lane = tid & 63;
  const int wr0 = (tid >> 6) * 4;
  for (int oc0 = 0; oc0 < COUT; oc0 += 64) {
    const int oc = oc0 + lane;
    const bool active = oc < COUT;
    const float bval = active ? bias[oc] : 0.f;
    float acc[4][8];
#pragma unroll
    for (int i = 0; i < 4; ++i)
#pragma unroll
      for (int j = 0; j < 8; ++j) acc[i][j] = 0.f;
#pragma unroll 1
    for (int ic = 0; ic < CIN; ++ic) {
      float wk[9];
#pragma unroll
      for (int t = 0; t < 9; ++t)
        wk[t] = active ? wT[(size_t)(ic * 9 + t) * COUTP + oc] : 0.f;
#pragma unroll
      for (int s = 0; s < 6; ++s) {
        const float4* row = (const float4*)&slab[(ic * 18 + wr0 + s) * 12];
        float4 A = row[0], B = row[1], C = row[2];
        float xv[10] = {A.x, A.y, A.z, A.w, B.x, B.y, B.z, B.w, C.x, C.y};
#pragma unroll
        for (int ky = 0; ky < 3; ++ky) {
          const int pr = s - ky;
          if (pr < 0 || pr > 3) continue;
#pragma unroll
          for (int kx = 0; kx < 3; ++kx) {
            const float w = wk[ky * 3 + kx];
#pragma unroll
            for (int cc = 0; cc < 8; ++cc)
              acc[pr][cc] = fmaf(xv[cc + kx], w, acc[pr][cc]);
          }
        }
      }
    }
    if (active) {
#pragma unroll
      for (int pr = 0; pr < 4; ++pr) {
        const int gr = gr0 + wr0 + pr;
#pragma unroll
        for (int cc = 0; cc < 8; ++cc) {
          float v = acc[pr][cc] + bval;
          if (RELU) v = fmaxf(v, 0.f);
          out[((size_t)gr * W + (gc0 + cc)) * COUTP + oc] = (OutT)v;
        }
      }
    }
  }
}

// ---------------- fp16 MFMA 3x3 conv, CIN=64, NHWC ----------------
// Block = 256 thr (4 waves), output tile 16x16 px. Halo 18x18x64 fp16 in LDS,
// 16B ic-chunks XOR-swizzled by (col&7) -> conflict-free ds_read_b128 A-frags.
// Wave w owns tile-rows 4w..4w+3 (M-tiles of 16 px = cols), all NT n-tiles.
// K-loop: 18 steps = 9 taps x 2 ic-halves, mfma_f32_16x16x32_f16.
template <int NT, int COUT, int COUTP, bool RELU, typename OutT>
__global__ __launch_bounds__(256)
void conv3x3_mfma_kernel(const _Float16* __restrict__ in, const half8* __restrict__ Bp,
                         const float* __restrict__ bias, OutT* __restrict__ out,
                         int H, int W) {
  __shared__ __align__(16) _Float16 slab[18 * 18 * 64];  // 41472 B
  const int tid = threadIdx.x;
  const int gr0 = blockIdx.y * 16, gc0 = blockIdx.x * 16;
  // stage halo: 18*18 px * 8 chunks of 16B, swizzled chunk' = chunk ^ (col&7)
  for (int i = tid; i < 18 * 18 * 8; i += 256) {
    int chunk = i & 7, px = i >> 3;
    int R = px / 18, C = px % 18;
    int gr = gr0 - 1 + R, gc = gc0 - 1 + C;
    half8 v = {0, 0, 0, 0, 0, 0, 0, 0};
    if (gr >= 0 && gr < H && gc >= 0 && gc < W)
      v = *(const half8*)(in + ((size_t)gr * W + gc) * 64 + chunk * 8);
    *(half8*)(slab + px * 64 + (chunk ^ (C & 7)) * 8) = v;
  }
  __syncthreads();
  const int lane = tid & 63;
  const int wv = tid >> 6;
  const int quad = lane >> 4;
  const int ln15 = lane & 15;
  f32x4 acc[4][NT];
  const f32x4 zz = {0.f, 0.f, 0.f, 0.f};
#pragma unroll
  for (int mt = 0; mt < 4; ++mt)
#pragma unroll
    for (int nt = 0; nt < NT; ++nt) acc[mt][nt] = zz;
#pragma unroll 1
  for (int s = 0; s < 18; ++s) {
    const int tap = s >> 1;
    const int dy = tap / 3;
    const int dx = tap - dy * 3;
    half8 bf[NT];
#pragma unroll
    for (int nt = 0; nt < NT; ++nt) bf[nt] = Bp[(s * NT + nt) * 64 + lane];
    const int C = dx + ln15;                       // halo col (A: m = lane&15)
    const int qsw = (((s & 1) * 4 + quad) ^ (C & 7));  // swizzled 16B chunk
    const _Float16* base = slab + C * 64 + qsw * 8;
    half8 af[4];
#pragma unroll
    for (int mt = 0; mt < 4; ++mt) {
      const int R = wv * 4 + mt + dy;              // halo row
      af[mt] = *(const half8*)(base + R * (18 * 64));
    }
#pragma unroll
    for (int mt = 0; mt < 4; ++mt)
#pragma unroll
      for (int nt = 0; nt < NT; ++nt)
        acc[mt][nt] = __builtin_amdgcn_mfma_f32_16x16x32_f16(af[mt], bf[nt], acc[mt][nt], 0, 0, 0);
  }
  // epilogue: D[m=quad*4+reg][n=lane&15]; m = tile col, tile row = wv*4+mt
#pragma unroll
  for (int nt = 0; nt < NT; ++nt) {
    const int oc = nt * 16 + ln15;
    const float bv = (oc < COUT) ? bias[oc] : 0.f;
#pragma unroll
    for (int mt = 0; mt < 4; ++mt) {
      const int gr = gr0 + wv * 4 + mt;
#pragma unroll
      for (int reg = 0; reg < 4; ++reg) {
        const int gc = gc0 + quad * 4 + reg;
        float v = acc[mt][nt][reg] + bv;
        if (RELU) v = fmaxf(v, 0.f);
        if (oc < COUTP) out[((size_t)gr * W + gc) * COUTP + oc] = (OutT)v;
      }
    }
  }
}

// ---------------- fused softmax(81) + 9x9 dynamic conv + nearest upsample ----------------
// f: fp16, (Hs*Ws, 88) padded; s: fp32 (Hs,Ws); writes cat channel ch at 512x512.
template <int RS>
__global__ void softdyn_kernel(const _Float16* __restrict__ f, const float* __restrict__ s,
                               float* __restrict__ cat, int Hs, int Ws, int ch) {
  int idx = blockIdx.x * blockDim.x + threadIdx.x;
  if (idx >= Hs * Ws) return;
  int r = idx / Ws, c = idx % Ws;
  const half8* fp = (const half8*)(f + (size_t)idx * 88);
  float sum = 0.f, y = 0.f;
#pragma unroll
  for (int k8 = 0; k8 < 11; ++k8) {
    half8 v8 = fp[k8];
#pragma unroll
    for (int q = 0; q < 8; ++q) {
      const int k = k8 * 8 + q;
      if (k >= 81) break;
      float e = __expf((float)v8[q]);
      int dy = k / 9, dx = k % 9;
      int rr = r + dy - 4, cc = c + dx - 4;
      float xv = (rr >= 0 && rr < Hs && cc >= 0 && cc < Ws) ? s[(size_t)rr * Ws + cc] : 0.f;
      sum += e;
      y = fmaf(e, xv, y);
    }
  }
  float o = y / sum;
  int R0 = r * RS, C0 = c * RS;
#pragma unroll
  for (int a = 0; a < RS; ++a)
#pragma unroll
    for (int b = 0; b < RS; ++b)
      cat[((size_t)(R0 + a) * 512 + (C0 + b)) * 5 + ch] = o;
}

// ---------------- final 64->1 conv ----------------
__global__ void conv5_kernel(const float* __restrict__ hid, const float* __restrict__ w,
                             const float* __restrict__ b, float* __restrict__ out,
                             int H, int W) {
  int idx = blockIdx.x * blockDim.x + threadIdx.x;
  if (idx >= H * W) return;
  int r = idx / W, c = idx % W;
  float acc = b[0];
#pragma unroll
  for (int ky = 0; ky < 3; ++ky) {
    int rr = r + ky - 1;
    if (rr < 0 || rr >= H) continue;
#pragma unroll
    for (int kx = 0; kx < 3; ++kx) {
      int cc = c + kx - 1;
      if (cc < 0 || cc >= W) continue;
      const float4* hp = (const float4*)(hid + ((size_t)rr * W + cc) * 64);
      const float* wp = w + (ky * 3 + kx);
#pragma unroll
      for (int i = 0; i < 16; ++i) {
        float4 h4 = hp[i];
        acc = fmaf(h4.x, wp[(i * 4 + 0) * 9], acc);
        acc = fmaf(h4.y, wp[(i * 4 + 1) * 9], acc);
        acc = fmaf(h4.z, wp[(i * 4 + 2) * 9], acc);
        acc = fmaf(h4.w, wp[(i * 4 + 3) * 9], acc);
      }
    }
  }
  out[idx] = acc;
}

extern "C" void kernel_launch(void* const* d_in, const int* in_sizes, int n_in,
                              void* d_out, int out_size, void* d_ws, size_t ws_size,
                              hipStream_t stream) {
  (void)in_sizes; (void)n_in; (void)out_size; (void)ws_size;
  const float* x   = (const float*)d_in[0];
  const float* g   = (const float*)d_in[1];
  const float* fWa = (const float*)d_in[2];
  const float* fba = (const float*)d_in[3];
  const float* fWb = (const float*)d_in[4];
  const float* fbb = (const float*)d_in[5];
  const float* fWc = (const float*)d_in[6];
  const float* fbc = (const float*)d_in[7];
  const float* W2a = (const float*)d_in[8];
  const float* b2a = (const float*)d_in[9];
  const float* W2b = (const float*)d_in[10];
  const float* b2b = (const float*)d_in[11];
  float* out = (float*)d_out;
  float* ws = (float*)d_ws;

  // carve (float units), total ~31.3M floats = 125 MB
  float* wTa   = ws;                    // 5*576 = 2880
  float* wTd   = wTa + 2880;            // 2880
  float* BpbF  = wTd + 2880;            // 5*18*4*512 halves = 92160 floats
  float* BpcF  = BpbF + 92160;          // 5*18*6*512 halves = 138240 floats
  float* s1    = BpcF + 138240;         // 131072
  float* s2    = s1 + 131072;           // 32768
  float* s3    = s2 + 32768;            // 8192
  float* cat   = s3 + 8192;             // 2621440
  float* h1F   = cat + 2621440;         // 512^2*64 halves = 8388608 floats
  float* h2F   = h1F + 8388608;         // 8388608
  float* fbF   = h2F + 8388608;         // 512^2*88 halves = 11534336 floats
  _Float16* h1 = (_Float16*)h1F;
  _Float16* h2 = (_Float16*)h2F;
  _Float16* fb = (_Float16*)fbF;
  const half8* Bpb = (const half8*)BpbF;   // 4608 half8 per scale
  const half8* Bpc = (const half8*)BpcF;   // 6912 half8 per scale
  float* hid = h1F;  // aliases h1+h2 (16777216 floats), used after scales

  // prep
  wtrans_kernel<<<dim3(3, 1, 5), 256, 0, stream>>>(fWa, wTa, 64, 1, 64, 576, 576);
  wtrans_kernel<<<dim3(12, 1, 1), 256, 0, stream>>>(W2a, wTd, 64, 5, 64, 2880, 2880);
  wpack_kernel<<<dim3(144, 1, 5), 256, 0, stream>>>(fWb, (_Float16*)BpbF, 64, 4, 36864, 36864);
  wpack_kernel<<<dim3(216, 1, 5), 256, 0, stream>>>(fWc, (_Float16*)BpcF, 81, 6, 46656, 55296);
  downsample_kernel<<<dim3(256, 1, 2), 256, 0, stream>>>(x, s1, 256, 256, 2, 512);
  downsample_kernel<<<dim3(64, 1, 2), 256, 0, stream>>>(x, s2, 128, 128, 4, 512);
  downsample_kernel<<<dim3(16, 1, 2), 256, 0, stream>>>(x, s3, 64, 64, 8, 512);

  const int HS_[5] = {512, 256, 128, 64, 512};
  for (int n = 0; n < 2; ++n) {
    const float* sins[5] = {x + (size_t)n * 262144, s1 + (size_t)n * 65536,
                            s2 + (size_t)n * 16384, s3 + (size_t)n * 4096,
                            g + (size_t)n * 262144};
    float* catn = cat + (size_t)n * 1310720;
    for (int i = 0; i < 5; ++i) {
      const int Hs = HS_[i];
      conv3x3_kernel<1, 64, 64, true, _Float16><<<dim3(Hs / 8, Hs / 16), 256, 0, stream>>>(
          sins[i], wTa + i * 576, fba + i * 64, h1, Hs, Hs);
      conv3x3_mfma_kernel<4, 64, 64, true, _Float16><<<dim3(Hs / 16, Hs / 16), 256, 0, stream>>>(
          h1, Bpb + (size_t)i * 4608, fbb + i * 64, h2, Hs, Hs);
      conv3x3_mfma_kernel<6, 81, 88, false, _Float16><<<dim3(Hs / 16, Hs / 16), 256, 0, stream>>>(
          h2, Bpc + (size_t)i * 6912, fbc + i * 81, fb, Hs, Hs);
      const int np = (Hs * Hs + 255) / 256;
      switch (i) {
        case 0: softdyn_kernel<1><<<np, 256, 0, stream>>>(fb, sins[i], catn, Hs, Hs, 0); break;
        case 1: softdyn_kernel<2><<<np, 256, 0, stream>>>(fb, sins[i], catn, Hs, Hs, 1); break;
        case 2: softdyn_kernel<4><<<np, 256, 0, stream>>>(fb, sins[i], catn, Hs, Hs, 2); break;
        case 3: softdyn_kernel<8><<<np, 256, 0, stream>>>(fb, sins[i], catn, Hs, Hs, 3); break;
        case 4: softdyn_kernel<1><<<np, 256, 0, stream>>>(fb, sins[i], catn, Hs, Hs, 4); break;
      }
    }
    conv3x3_kernel<5, 64, 64, true, float><<<dim3(64, 32), 256, 0, stream>>>(
        catn, wTd, b2a, hid, 512, 512);
    conv5_kernel<<<dim3(1024, 1, 1), 256, 0, stream>>>(hid, W2b, b2b,
                                                       out + (size_t)n * 262144, 512, 512);
  }
}

// Round 3
// 1028.887 us; speedup vs baseline: 4.9226x; 1.0934x over previous
//
#include <hip/hip_runtime.h>
#include <math.h>

typedef _Float16 half8 __attribute__((ext_vector_type(8)));
typedef float f32x4 __attribute__((ext_vector_type(4)));

// ---------------- weight transpose: (COUT,CIN,3,3) -> (CIN*9, COUTP), fp32 ----------------
__global__ void wtrans_kernel(const float* __restrict__ src, float* __restrict__ dst,
                              int COUT, int CIN, int COUTP,
                              int per_scale_src, int per_scale_dst) {
  const int s = blockIdx.z;
  src += (size_t)s * per_scale_src;
  dst += (size_t)s * per_scale_dst;
  const int total = COUT * CIN * 9;
  for (int idx = blockIdx.x * blockDim.x + threadIdx.x; idx < total;
       idx += gridDim.x * blockDim.x) {
    int t  = idx % 9;
    int ic = (idx / 9) % CIN;
    int oc = idx / (9 * CIN);
    dst[(ic * 9 + t) * COUTP + oc] = src[idx];
  }
}

// ---------------- weight pack for MFMA (as round 2, verified) ----------------
__global__ void wpack_kernel(const float* __restrict__ src, _Float16* __restrict__ dst,
                             int COUT, int NT, int per_scale_src, int per_scale_dst) {
  const int sc = blockIdx.z;
  src += (size_t)sc * per_scale_src;
  dst += (size_t)sc * per_scale_dst;
  const int total = 18 * NT * 64 * 8;
  for (int idx = blockIdx.x * blockDim.x + threadIdx.x; idx < total;
       idx += gridDim.x * blockDim.x) {
    int j = idx & 7;
    int lane = (idx >> 3) & 63;
    int rest = idx >> 9;
    int t = rest % NT;
    int s = rest / NT;
    int oc = t * 16 + (lane & 15);
    int tap = s >> 1;
    int ic = (s & 1) * 32 + ((lane >> 4) & 3) * 8 + j;
    float v = (oc < COUT) ? src[((size_t)oc * 64 + ic) * 9 + tap] : 0.f;
    dst[idx] = (_Float16)v;
  }
}

// ---------------- nearest downsample (C=1) ----------------
__global__ void downsample_kernel(const float* __restrict__ in, float* __restrict__ out,
                                  int Hs, int Ws, int r, int W) {
  const float* ip = in + (size_t)blockIdx.z * W * W;
  float* op = out + (size_t)blockIdx.z * Hs * Ws;
  int idx = blockIdx.x * blockDim.x + threadIdx.x;
  if (idx < Hs * Ws) {
    int rr = idx / Ws, cc = idx % Ws;
    op[idx] = ip[(size_t)(rr * r) * W + cc * r];
  }
}

// ---------------- shared MFMA K-loop + epilogue (r2-verified layout) ----------------
// slab: 18x18 px, 64 ch fp16, 16B chunks XOR-swizzled by (col&7).
template <int NT, int COUT, int COUTP, bool RELU, typename OutT>
__device__ __forceinline__ void mfma_body(const _Float16* slab, const half8* __restrict__ Bp,
                                          const float* __restrict__ bias,
                                          OutT* __restrict__ out,
                                          int H, int W, int gr0, int gc0, int tid) {
  const int lane = tid & 63;
  const int wv = tid >> 6;
  const int quad = lane >> 4;
  const int ln15 = lane & 15;
  f32x4 acc[4][NT];
  const f32x4 zz = {0.f, 0.f, 0.f, 0.f};
#pragma unroll
  for (int mt = 0; mt < 4; ++mt)
#pragma unroll
    for (int nt = 0; nt < NT; ++nt) acc[mt][nt] = zz;
#pragma unroll 1
  for (int s = 0; s < 18; ++s) {
    const int tap = s >> 1;
    const int dy = tap / 3;
    const int dx = tap - dy * 3;
    half8 bf[NT];
#pragma unroll
    for (int nt = 0; nt < NT; ++nt) bf[nt] = Bp[(s * NT + nt) * 64 + lane];
    const int C = dx + ln15;
    const int qsw = (((s & 1) * 4 + quad) ^ (C & 7));
    const _Float16* base = slab + C * 64 + qsw * 8;
    half8 af[4];
#pragma unroll
    for (int mt = 0; mt < 4; ++mt) {
      const int R = wv * 4 + mt + dy;
      af[mt] = *(const half8*)(base + R * (18 * 64));
    }
#pragma unroll
    for (int mt = 0; mt < 4; ++mt)
#pragma unroll
      for (int nt = 0; nt < NT; ++nt)
        acc[mt][nt] = __builtin_amdgcn_mfma_f32_16x16x32_f16(af[mt], bf[nt], acc[mt][nt], 0, 0, 0);
  }
#pragma unroll
  for (int nt = 0; nt < NT; ++nt) {
    const int oc = nt * 16 + ln15;
    const float bv = (oc < COUT) ? bias[oc] : 0.f;
#pragma unroll
    for (int mt = 0; mt < 4; ++mt) {
      const int gr = gr0 + wv * 4 + mt;
#pragma unroll
      for (int reg = 0; reg < 4; ++reg) {
        const int gc = gc0 + quad * 4 + reg;
        float v = acc[mt][nt][reg] + bv;
        if (RELU) v = fmaxf(v, 0.f);
        if (oc < COUTP) out[((size_t)gr * W + gc) * COUTP + oc] = (OutT)v;
      }
    }
  }
}

// ---------------- fused conv1(1->64,relu) + conv2(64->64,relu) MFMA, z=batch ----------------
__global__ __launch_bounds__(256)
void conv12_mfma_kernel(const float* __restrict__ x0, int srcStride,
                        const float* __restrict__ wa,   // [t*64+oc]
                        const float* __restrict__ ba,   // [64]
                        const half8* __restrict__ Bp,   // conv2 pack
                        const float* __restrict__ bb,   // [64]
                        _Float16* __restrict__ out,     // h2, batch stride H*W*64
                        int H, int W) {
  __shared__ __align__(16) _Float16 slab[18 * 18 * 64];
  __shared__ float xs[20 * 20];
  const int n = blockIdx.z;
  const float* in = x0 + (size_t)n * srcStride;
  out += (size_t)n * H * W * 64;
  const int tid = threadIdx.x;
  const int gr0 = blockIdx.y * 16, gc0 = blockIdx.x * 16;
  for (int i = tid; i < 400; i += 256) {
    int R = i / 20, C = i % 20;
    int gr = gr0 - 2 + R, gc = gc0 - 2 + C;
    xs[i] = (gr >= 0 && gr < H && gc >= 0 && gc < W) ? in[(size_t)gr * W + gc] : 0.f;
  }
  __syncthreads();
  const int lane = tid & 63;
  const int wv = tid >> 6;
  float wk[9];
#pragma unroll
  for (int t = 0; t < 9; ++t) wk[t] = wa[t * 64 + lane];
  const float bv = ba[lane];
  const int chunkbase = lane >> 3;
#pragma unroll 1
  for (int i = 0; i < 81; ++i) {
    int px = wv * 81 + i;
    int R = px / 18, C = px - R * 18;
    int gr = gr0 - 1 + R, gc = gc0 - 1 + C;
    float acc = bv;
#pragma unroll
    for (int ky = 0; ky < 3; ++ky)
#pragma unroll
      for (int kx = 0; kx < 3; ++kx)
        acc = fmaf(xs[(R + ky) * 20 + (C + kx)], wk[ky * 3 + kx], acc);
    float v = (gr >= 0 && gr < H && gc >= 0 && gc < W) ? fmaxf(acc, 0.f) : 0.f;
    slab[px * 64 + ((chunkbase ^ (C & 7)) * 8) + (lane & 7)] = (_Float16)v;
  }
  __syncthreads();
  mfma_body<4, 64, 64, true, _Float16>(slab, Bp, bb, out, H, W, gr0, gc0, tid);
}

// ---------------- conv3 (64->81) MFMA, slab staged from global h2 ----------------
template <int NT, int COUT, int COUTP, bool RELU, typename OutT>
__global__ __launch_bounds__(256)
void conv3x3_mfma_kernel(const _Float16* __restrict__ in, const half8* __restrict__ Bp,
                         const float* __restrict__ bias, OutT* __restrict__ out,
                         int H, int W) {
  __shared__ __align__(16) _Float16 slab[18 * 18 * 64];
  const int tid = threadIdx.x;
  const int gr0 = blockIdx.y * 16, gc0 = blockIdx.x * 16;
  for (int i = tid; i < 18 * 18 * 8; i += 256) {
    int chunk = i & 7, px = i >> 3;
    int R = px / 18, C = px % 18;
    int gr = gr0 - 1 + R, gc = gc0 - 1 + C;
    half8 v = {0, 0, 0, 0, 0, 0, 0, 0};
    if (gr >= 0 && gr < H && gc >= 0 && gc < W)
      v = *(const half8*)(in + ((size_t)gr * W + gc) * 64 + chunk * 8);
    *(half8*)(slab + px * 64 + (chunk ^ (C & 7)) * 8) = v;
  }
  __syncthreads();
  mfma_body<NT, COUT, COUTP, RELU, OutT>(slab, Bp, bias, out, H, W, gr0, gc0, tid);
}

// ---------------- fused softmax(81) + 9x9 dynamic conv + nearest upsample ----------------
template <int RS>
__global__ void softdyn_kernel(const _Float16* __restrict__ f, const float* __restrict__ s,
                               float* __restrict__ cat, int Hs, int Ws, int ch) {
  int idx = blockIdx.x * blockDim.x + threadIdx.x;
  if (idx >= Hs * Ws) return;
  int r = idx / Ws, c = idx % Ws;
  const half8* fp = (const half8*)(f + (size_t)idx * 88);
  float sum = 0.f, y = 0.f;
#pragma unroll
  for (int k8 = 0; k8 < 11; ++k8) {
    half8 v8 = fp[k8];
#pragma unroll
    for (int q = 0; q < 8; ++q) {
      const int k = k8 * 8 + q;
      if (k >= 81) break;
      float e = __expf((float)v8[q]);
      int dy = k / 9, dx = k % 9;
      int rr = r + dy - 4, cc = c + dx - 4;
      float xv = (rr >= 0 && rr < Hs && cc >= 0 && cc < Ws) ? s[(size_t)rr * Ws + cc] : 0.f;
      sum += e;
      y = fmaf(e, xv, y);
    }
  }
  float o = y / sum;
  int R0 = r * RS, C0 = c * RS;
#pragma unroll
  for (int a = 0; a < RS; ++a)
#pragma unroll
    for (int b = 0; b < RS; ++b)
      cat[((size_t)(R0 + a) * 512 + (C0 + b)) * 5 + ch] = o;
}

// ---------------- fused tail: cat(5) -> conv3x3 relu (64, LDS-only) -> conv3x3 -> 1 ----------------
__global__ __launch_bounds__(256)
void tail_fused_kernel(const float* __restrict__ cat,
                       const float* __restrict__ wTd,   // [(ic*9+t)*64+oc], 45x64
                       const float* __restrict__ b2a,   // [64]
                       const float* __restrict__ w2b,   // [oc*9+t]
                       const float* __restrict__ b2b,
                       float* __restrict__ out) {
  __shared__ __align__(16) _Float16 hid[18 * 18 * 64];   // 41472 B
  __shared__ float cs[20 * 20 * 5];                      // 8000 B
  const int n = blockIdx.z;
  const float* cin = cat + (size_t)n * (512 * 512 * 5);
  float* op = out + (size_t)n * (512 * 512);
  const int tid = threadIdx.x;
  const int gr0 = blockIdx.y * 16, gc0 = blockIdx.x * 16;
  for (int i = tid; i < 2000; i += 256) {
    int px = i / 5, ic = i - px * 5;
    int R = px / 20, C = px - R * 20;
    int gr = gr0 - 2 + R, gc = gc0 - 2 + C;
    cs[i] = (gr >= 0 && gr < 512 && gc >= 0 && gc < 512)
                ? cin[((size_t)gr * 512 + gc) * 5 + ic] : 0.f;
  }
  __syncthreads();
  const int lane = tid & 63;
  const int wv = tid >> 6;
  float wk[45];
#pragma unroll
  for (int t = 0; t < 45; ++t) wk[t] = wTd[t * 64 + lane];
  const float bv = b2a[lane];
  const int chunkbase = lane >> 3;
#pragma unroll 1
  for (int i = 0; i < 81; ++i) {
    int px = wv * 81 + i;
    int R = px / 18, C = px - R * 18;
    int gr = gr0 - 1 + R, gc = gc0 - 1 + C;
    float acc = bv;
#pragma unroll
    for (int ic = 0; ic < 5; ++ic)
#pragma unroll
      for (int ky = 0; ky < 3; ++ky)
#pragma unroll
        for (int kx = 0; kx < 3; ++kx)
          acc = fmaf(cs[((R + ky) * 20 + (C + kx)) * 5 + ic], wk[ic * 9 + ky * 3 + kx], acc);
    float v = (gr >= 0 && gr < 512 && gc >= 0 && gc < 512) ? fmaxf(acc, 0.f) : 0.f;
    hid[px * 64 + ((chunkbase ^ (C & 7)) * 8) + (lane & 7)] = (_Float16)v;
  }
  __syncthreads();
  // stage 2: one output px per thread (16x16)
  const int r = tid >> 4, c = tid & 15;
  float acc = b2b[0];
#pragma unroll
  for (int ky = 0; ky < 3; ++ky)
#pragma unroll
    for (int kx = 0; kx < 3; ++kx) {
      const int R = r + ky, C = c + kx;
      const _Float16* hp = hid + (R * 18 + C) * 64;
      const int tap = ky * 3 + kx;
#pragma unroll
      for (int j = 0; j < 8; ++j) {
        half8 h = *(const half8*)(hp + ((j ^ (C & 7)) * 8));
#pragma unroll
        for (int q = 0; q < 8; ++q)
          acc = fmaf((float)h[q], w2b[(j * 8 + q) * 9 + tap], acc);
      }
    }
  op[(size_t)(gr0 + r) * 512 + (gc0 + c)] = acc;
}

extern "C" void kernel_launch(void* const* d_in, const int* in_sizes, int n_in,
                              void* d_out, int out_size, void* d_ws, size_t ws_size,
                              hipStream_t stream) {
  (void)in_sizes; (void)n_in; (void)out_size; (void)ws_size;
  const float* x   = (const float*)d_in[0];
  const float* g   = (const float*)d_in[1];
  const float* fWa = (const float*)d_in[2];
  const float* fba = (const float*)d_in[3];
  const float* fWb = (const float*)d_in[4];
  const float* fbb = (const float*)d_in[5];
  const float* fWc = (const float*)d_in[6];
  const float* fbc = (const float*)d_in[7];
  const float* W2a = (const float*)d_in[8];
  const float* b2a = (const float*)d_in[9];
  const float* W2b = (const float*)d_in[10];
  const float* b2b = (const float*)d_in[11];
  float* out = (float*)d_out;
  float* ws = (float*)d_ws;

  // carve (float units), total ~31.3M floats = 125 MB
  float* wTa   = ws;                    // 5*576 = 2880
  float* wTd   = wTa + 2880;            // 2880
  float* BpbF  = wTd + 2880;            // 92160
  float* BpcF  = BpbF + 92160;          // 138240
  float* s1    = BpcF + 138240;         // 131072
  float* s2    = s1 + 131072;           // 32768
  float* s3    = s2 + 32768;            // 8192
  float* cat   = s3 + 8192;             // 2621440
  float* h2F   = cat + 2621440;         // 2 batches * 512^2*64 halves = 16777216 floats
  float* fbF   = h2F + 16777216;        // 1 batch 512^2*88 halves = 11534336 floats
  _Float16* h2 = (_Float16*)h2F;
  _Float16* fb = (_Float16*)fbF;
  const half8* Bpb = (const half8*)BpbF;
  const half8* Bpc = (const half8*)BpcF;

  wtrans_kernel<<<dim3(3, 1, 5), 256, 0, stream>>>(fWa, wTa, 64, 1, 64, 576, 576);
  wtrans_kernel<<<dim3(12, 1, 1), 256, 0, stream>>>(W2a, wTd, 64, 5, 64, 2880, 2880);
  wpack_kernel<<<dim3(144, 1, 5), 256, 0, stream>>>(fWb, (_Float16*)BpbF, 64, 4, 36864, 36864);
  wpack_kernel<<<dim3(216, 1, 5), 256, 0, stream>>>(fWc, (_Float16*)BpcF, 81, 6, 46656, 55296);
  downsample_kernel<<<dim3(256, 1, 2), 256, 0, stream>>>(x, s1, 256, 256, 2, 512);
  downsample_kernel<<<dim3(64, 1, 2), 256, 0, stream>>>(x, s2, 128, 128, 4, 512);
  downsample_kernel<<<dim3(16, 1, 2), 256, 0, stream>>>(x, s3, 64, 64, 8, 512);

  const int HS_[5] = {512, 256, 128, 64, 512};
  const float* srcs[5] = {x, s1, s2, s3, g};
  const int strides[5] = {262144, 65536, 16384, 4096, 262144};
  for (int i = 0; i < 5; ++i) {
    const int Hs = HS_[i];
    conv12_mfma_kernel<<<dim3(Hs / 16, Hs / 16, 2), 256, 0, stream>>>(
        srcs[i], strides[i], wTa + i * 576, fba + i * 64,
        Bpb + (size_t)i * 4608, fbb + i * 64, h2, Hs, Hs);
    for (int n = 0; n < 2; ++n) {
      conv3x3_mfma_kernel<6, 81, 88, false, _Float16><<<dim3(Hs / 16, Hs / 16), 256, 0, stream>>>(
          h2 + (size_t)n * Hs * Hs * 64, Bpc + (size_t)i * 6912, fbc + i * 81, fb, Hs, Hs);
      const float* sn = srcs[i] + (size_t)n * strides[i];
      float* catn = cat + (size_t)n * 1310720;
      const int np = (Hs * Hs + 255) / 256;
      switch (i) {
        case 0: softdyn_kernel<1><<<np, 256, 0, stream>>>(fb, sn, catn, Hs, Hs, 0); break;
        case 1: softdyn_kernel<2><<<np, 256, 0, stream>>>(fb, sn, catn, Hs, Hs, 1); break;
        case 2: softdyn_kernel<4><<<np, 256, 0, stream>>>(fb, sn, catn, Hs, Hs, 2); break;
        case 3: softdyn_kernel<8><<<np, 256, 0, stream>>>(fb, sn, catn, Hs, Hs, 3); break;
        case 4: softdyn_kernel<1><<<np, 256, 0, stream>>>(fb, sn, catn, Hs, Hs, 4); break;
      }
    }
  }
  tail_fused_kernel<<<dim3(32, 32, 2), 256, 0, stream>>>(cat, wTd, b2a, W2b, b2b, out);
}

// Round 4
// 845.474 us; speedup vs baseline: 5.9905x; 1.2169x over previous
//
#include <hip/hip_runtime.h>
#include <math.h>

typedef _Float16 half8 __attribute__((ext_vector_type(8)));
typedef float f32x4 __attribute__((ext_vector_type(4)));

// ---------------- weight transpose: (COUT,CIN,3,3) -> (CIN*9, COUTP), fp32 ----------------
__global__ void wtrans_kernel(const float* __restrict__ src, float* __restrict__ dst,
                              int COUT, int CIN, int COUTP,
                              int per_scale_src, int per_scale_dst) {
  const int s = blockIdx.z;
  src += (size_t)s * per_scale_src;
  dst += (size_t)s * per_scale_dst;
  const int total = COUT * CIN * 9;
  for (int idx = blockIdx.x * blockDim.x + threadIdx.x; idx < total;
       idx += gridDim.x * blockDim.x) {
    int t  = idx % 9;
    int ic = (idx / 9) % CIN;
    int oc = idx / (9 * CIN);
    dst[(ic * 9 + t) * COUTP + oc] = src[idx];
  }
}

// ---------------- weight pack for MFMA (r2-verified layout) ----------------
// Bp[((s*NT+t)*64+lane)*8+j]: oc=t*16+(lane&15), tap=s>>1, ic=(s&1)*32+quad*8+j
__global__ void wpack_kernel(const float* __restrict__ src, _Float16* __restrict__ dst,
                             int COUT, int NT, int per_scale_src, int per_scale_dst) {
  const int sc = blockIdx.z;
  src += (size_t)sc * per_scale_src;
  dst += (size_t)sc * per_scale_dst;
  const int total = 18 * NT * 64 * 8;
  for (int idx = blockIdx.x * blockDim.x + threadIdx.x; idx < total;
       idx += gridDim.x * blockDim.x) {
    int j = idx & 7;
    int lane = (idx >> 3) & 63;
    int rest = idx >> 9;
    int t = rest % NT;
    int s = rest / NT;
    int oc = t * 16 + (lane & 15);
    int tap = s >> 1;
    int ic = (s & 1) * 32 + ((lane >> 4) & 3) * 8 + j;
    float v = (oc < COUT) ? src[((size_t)oc * 64 + ic) * 9 + tap] : 0.f;
    dst[idx] = (_Float16)v;
  }
}

// ---------------- pack W2a (64,5,3,3) for tail stage-1: K=45 pad 64, 2 k-steps, 4 n-tiles ----
__global__ void wpack_tail1_kernel(const float* __restrict__ W2a, _Float16* __restrict__ dst) {
  int idx = blockIdx.x * blockDim.x + threadIdx.x;  // 4096 total
  if (idx >= 4096) return;
  int j = idx & 7, lane = (idx >> 3) & 63;
  int nt = (idx >> 9) & 3, s = idx >> 11;
  int oc = nt * 16 + (lane & 15);
  int k = s * 32 + ((lane >> 4) & 3) * 8 + j;
  float v = 0.f;
  if (k < 45) {
    int ic = k / 9, tap = k - ic * 9;
    v = W2a[(oc * 5 + ic) * 9 + tap];
  }
  dst[idx] = (_Float16)v;
}

// ---------------- nearest downsample (C=1) ----------------
__global__ void downsample_kernel(const float* __restrict__ in, float* __restrict__ out,
                                  int Hs, int Ws, int r, int W) {
  const float* ip = in + (size_t)blockIdx.z * W * W;
  float* op = out + (size_t)blockIdx.z * Hs * Ws;
  int idx = blockIdx.x * blockDim.x + threadIdx.x;
  if (idx < Hs * Ws) {
    int rr = idx / Ws, cc = idx % Ws;
    op[idx] = ip[(size_t)(rr * r) * W + cc * r];
  }
}

// ---------------- shared MFMA K-loop + epilogue (r2-verified layout) ----------------
template <int NT, int COUT, int COUTP, bool RELU, typename OutT>
__device__ __forceinline__ void mfma_body(const _Float16* slab, const half8* __restrict__ Bp,
                                          const float* __restrict__ bias,
                                          OutT* __restrict__ out,
                                          int H, int W, int gr0, int gc0, int tid) {
  const int lane = tid & 63;
  const int wv = tid >> 6;
  const int quad = lane >> 4;
  const int ln15 = lane & 15;
  f32x4 acc[4][NT];
  const f32x4 zz = {0.f, 0.f, 0.f, 0.f};
#pragma unroll
  for (int mt = 0; mt < 4; ++mt)
#pragma unroll
    for (int nt = 0; nt < NT; ++nt) acc[mt][nt] = zz;
#pragma unroll 1
  for (int s = 0; s < 18; ++s) {
    const int tap = s >> 1;
    const int dy = tap / 3;
    const int dx = tap - dy * 3;
    half8 bf[NT];
#pragma unroll
    for (int nt = 0; nt < NT; ++nt) bf[nt] = Bp[(s * NT + nt) * 64 + lane];
    const int C = dx + ln15;
    const int qsw = (((s & 1) * 4 + quad) ^ (C & 7));
    const _Float16* base = slab + C * 64 + qsw * 8;
    half8 af[4];
#pragma unroll
    for (int mt = 0; mt < 4; ++mt) {
      const int R = wv * 4 + mt + dy;
      af[mt] = *(const half8*)(base + R * (18 * 64));
    }
#pragma unroll
    for (int mt = 0; mt < 4; ++mt)
#pragma unroll
      for (int nt = 0; nt < NT; ++nt)
        acc[mt][nt] = __builtin_amdgcn_mfma_f32_16x16x32_f16(af[mt], bf[nt], acc[mt][nt], 0, 0, 0);
  }
#pragma unroll
  for (int nt = 0; nt < NT; ++nt) {
    const int oc = nt * 16 + ln15;
    const float bv = (oc < COUT) ? bias[oc] : 0.f;
#pragma unroll
    for (int mt = 0; mt < 4; ++mt) {
      const int gr = gr0 + wv * 4 + mt;
#pragma unroll
      for (int reg = 0; reg < 4; ++reg) {
        const int gc = gc0 + quad * 4 + reg;
        float v = acc[mt][nt][reg] + bv;
        if (RELU) v = fmaxf(v, 0.f);
        if (oc < COUTP) out[((size_t)gr * W + gc) * COUTP + oc] = (OutT)v;
      }
    }
  }
}

// ---------------- fused conv1(1->64,relu) + conv2(64->64,relu) MFMA, z=batch ----------------
__global__ __launch_bounds__(256)
void conv12_mfma_kernel(const float* __restrict__ x0, int srcStride,
                        const float* __restrict__ wa,   // [t*64+oc]
                        const float* __restrict__ ba,   // [64]
                        const half8* __restrict__ Bp,   // conv2 pack
                        const float* __restrict__ bb,   // [64]
                        _Float16* __restrict__ out,     // h2, batch stride H*W*64
                        int H, int W) {
  __shared__ __align__(16) _Float16 slab[18 * 18 * 64];
  __shared__ float xs[20 * 20];
  const int n = blockIdx.z;
  const float* in = x0 + (size_t)n * srcStride;
  out += (size_t)n * H * W * 64;
  const int tid = threadIdx.x;
  const int gr0 = blockIdx.y * 16, gc0 = blockIdx.x * 16;
  for (int i = tid; i < 400; i += 256) {
    int R = i / 20, C = i % 20;
    int gr = gr0 - 2 + R, gc = gc0 - 2 + C;
    xs[i] = (gr >= 0 && gr < H && gc >= 0 && gc < W) ? in[(size_t)gr * W + gc] : 0.f;
  }
  __syncthreads();
  const int lane = tid & 63;
  const int wv = tid >> 6;
  float wk[9];
#pragma unroll
  for (int t = 0; t < 9; ++t) wk[t] = wa[t * 64 + lane];
  const float bv = ba[lane];
  const int chunkbase = lane >> 3;
  // conv1: sliding 3x3 window, 3 LDS broadcast reads per px
#pragma unroll 1
  for (int R = wv; R < 18; R += 4) {
    const int gr = gr0 - 1 + R;
    const bool grok = (gr >= 0 && gr < H);
    const float* r0 = xs + R * 20;
    float x00 = r0[0],  x01 = r0[1];
    float x10 = r0[20], x11 = r0[21];
    float x20 = r0[40], x21 = r0[41];
#pragma unroll 1
    for (int C = 0; C < 18; ++C) {
      float x02 = r0[C + 2], x12 = r0[20 + C + 2], x22 = r0[40 + C + 2];
      float acc = bv;
      acc = fmaf(x00, wk[0], acc); acc = fmaf(x01, wk[1], acc); acc = fmaf(x02, wk[2], acc);
      acc = fmaf(x10, wk[3], acc); acc = fmaf(x11, wk[4], acc); acc = fmaf(x12, wk[5], acc);
      acc = fmaf(x20, wk[6], acc); acc = fmaf(x21, wk[7], acc); acc = fmaf(x22, wk[8], acc);
      const int gc = gc0 - 1 + C;
      float v = (grok && gc >= 0 && gc < W) ? fmaxf(acc, 0.f) : 0.f;
      slab[(R * 18 + C) * 64 + ((chunkbase ^ (C & 7)) * 8) + (lane & 7)] = (_Float16)v;
      x00 = x01; x01 = x02; x10 = x11; x11 = x12; x20 = x21; x21 = x22;
    }
  }
  __syncthreads();
  mfma_body<4, 64, 64, true, _Float16>(slab, Bp, bb, out, H, W, gr0, gc0, tid);
}

// ---------------- conv3 (64->81) MFMA, slab staged from global h2 ----------------
template <int NT, int COUT, int COUTP, bool RELU, typename OutT>
__global__ __launch_bounds__(256)
void conv3x3_mfma_kernel(const _Float16* __restrict__ in, const half8* __restrict__ Bp,
                         const float* __restrict__ bias, OutT* __restrict__ out,
                         int H, int W) {
  __shared__ __align__(16) _Float16 slab[18 * 18 * 64];
  const int tid = threadIdx.x;
  const int gr0 = blockIdx.y * 16, gc0 = blockIdx.x * 16;
  for (int i = tid; i < 18 * 18 * 8; i += 256) {
    int chunk = i & 7, px = i >> 3;
    int R = px / 18, C = px % 18;
    int gr = gr0 - 1 + R, gc = gc0 - 1 + C;
    half8 v = {0, 0, 0, 0, 0, 0, 0, 0};
    if (gr >= 0 && gr < H && gc >= 0 && gc < W)
      v = *(const half8*)(in + ((size_t)gr * W + gc) * 64 + chunk * 8);
    *(half8*)(slab + px * 64 + (chunk ^ (C & 7)) * 8) = v;
  }
  __syncthreads();
  mfma_body<NT, COUT, COUTP, RELU, OutT>(slab, Bp, bias, out, H, W, gr0, gc0, tid);
}

// ---------------- fused softmax(81) + 9x9 dynamic conv + nearest upsample ----------------
template <int RS>
__global__ void softdyn_kernel(const _Float16* __restrict__ f, const float* __restrict__ s,
                               float* __restrict__ cat, int Hs, int Ws, int ch) {
  int idx = blockIdx.x * blockDim.x + threadIdx.x;
  if (idx >= Hs * Ws) return;
  int r = idx / Ws, c = idx % Ws;
  const half8* fp = (const half8*)(f + (size_t)idx * 88);
  float sum = 0.f, y = 0.f;
#pragma unroll
  for (int k8 = 0; k8 < 11; ++k8) {
    half8 v8 = fp[k8];
#pragma unroll
    for (int q = 0; q < 8; ++q) {
      const int k = k8 * 8 + q;
      if (k >= 81) break;
      float e = __expf((float)v8[q]);
      int dy = k / 9, dx = k % 9;
      int rr = r + dy - 4, cc = c + dx - 4;
      float xv = (rr >= 0 && rr < Hs && cc >= 0 && cc < Ws) ? s[(size_t)rr * Ws + cc] : 0.f;
      sum += e;
      y = fmaf(e, xv, y);
    }
  }
  float o = y / sum;
  int R0 = r * RS, C0 = c * RS;
#pragma unroll
  for (int a = 0; a < RS; ++a)
#pragma unroll
    for (int b = 0; b < RS; ++b)
      cat[((size_t)(R0 + a) * 512 + (C0 + b)) * 5 + ch] = o;
}

// ---------------- fused tail: cat(5) -> MFMA 5->64 relu (LDS) -> MFMA 64->1 ----------------
__global__ __launch_bounds__(256)
void tail_fused_kernel(const float* __restrict__ cat,
                       const half8* __restrict__ BpA,   // stage1 pack: 2 ks x 4 nt
                       const float* __restrict__ b2a,   // [64]
                       const half8* __restrict__ BpB,   // stage2 pack: 18 ks x 1 nt
                       const float* __restrict__ b2b,
                       float* __restrict__ out) {
  __shared__ float cs[20 * 20 * 5];                      // MUST be first (gather clamps to it)
  __shared__ __align__(16) _Float16 hid[18 * 18 * 64];
  const int n = blockIdx.z;
  const float* cin = cat + (size_t)n * (512 * 512 * 5);
  float* op = out + (size_t)n * (512 * 512);
  const int tid = threadIdx.x;
  const int gr0 = blockIdx.y * 16, gc0 = blockIdx.x * 16;
  for (int i = tid; i < 2000; i += 256) {
    int px = i / 5, ic = i - px * 5;
    int R = px / 20, C = px - R * 20;
    int gr = gr0 - 2 + R, gc = gc0 - 2 + C;
    cs[i] = (gr >= 0 && gr < 512 && gc >= 0 && gc < 512)
                ? cin[((size_t)gr * 512 + gc) * 5 + ic] : 0.f;
  }
  __syncthreads();
  const int lane = tid & 63;
  const int wv = tid >> 6;
  const int quad = lane >> 4;
  const int ln15 = lane & 15;
  // stage 1: implicit GEMM, M=324 px (21 m-tiles), K=45 pad 64 (2 steps), N=64
  int goff[2][8];
  bool gok[2][8];
#pragma unroll
  for (int s = 0; s < 2; ++s)
#pragma unroll
    for (int j = 0; j < 8; ++j) {
      int k = s * 32 + quad * 8 + j;
      bool ok = (k < 45);
      int ic = k / 9;
      int tap = k - ic * 9;
      int dy = tap / 3, dx = tap - dy * 3;
      goff[s][j] = ok ? ((dy * 20 + dx) * 5 + ic) : 0;
      gok[s][j] = ok;
    }
  half8 bfA[2][4];
#pragma unroll
  for (int s = 0; s < 2; ++s)
#pragma unroll
    for (int nt = 0; nt < 4; ++nt) bfA[s][nt] = BpA[(s * 4 + nt) * 64 + lane];
  float bvA[4];
#pragma unroll
  for (int nt = 0; nt < 4; ++nt) bvA[nt] = b2a[nt * 16 + ln15];
  const f32x4 zz = {0.f, 0.f, 0.f, 0.f};
#pragma unroll 1
  for (int mt = wv; mt < 21; mt += 4) {
    int px = mt * 16 + ln15;
    int pc = (px < 323) ? px : 323;
    int base = (pc / 18) * 100 + (pc % 18) * 5;  // (R*20+C)*5
    f32x4 acc1[4] = {zz, zz, zz, zz};
#pragma unroll
    for (int s = 0; s < 2; ++s) {
      half8 af;
#pragma unroll
      for (int j = 0; j < 8; ++j) {
        float a = gok[s][j] ? cs[base + goff[s][j]] : 0.f;
        af[j] = (_Float16)a;
      }
#pragma unroll
      for (int nt = 0; nt < 4; ++nt)
        acc1[nt] = __builtin_amdgcn_mfma_f32_16x16x32_f16(af, bfA[s][nt], acc1[nt], 0, 0, 0);
    }
#pragma unroll
    for (int nt = 0; nt < 4; ++nt) {
      const int oc = nt * 16 + ln15;
#pragma unroll
      for (int reg = 0; reg < 4; ++reg) {
        int p2 = mt * 16 + quad * 4 + reg;
        if (p2 < 324) {
          int R = p2 / 18, C = p2 - R * 18;
          int gr = gr0 - 1 + R, gc = gc0 - 1 + C;
          float v = (gr >= 0 && gr < 512 && gc >= 0 && gc < 512)
                        ? fmaxf(acc1[nt][reg] + bvA[nt], 0.f) : 0.f;
          hid[p2 * 64 + (((oc >> 3) ^ (C & 7)) * 8) + (oc & 7)] = (_Float16)v;
        }
      }
    }
  }
  __syncthreads();
  // stage 2: 64->1 via standard MFMA body (NT=1; only oc==0 lanes store)
  mfma_body<1, 1, 1, false, float>(hid, BpB, b2b, op, 512, 512, gr0, gc0, tid);
}

extern "C" void kernel_launch(void* const* d_in, const int* in_sizes, int n_in,
                              void* d_out, int out_size, void* d_ws, size_t ws_size,
                              hipStream_t stream) {
  (void)in_sizes; (void)n_in; (void)out_size; (void)ws_size;
  const float* x   = (const float*)d_in[0];
  const float* g   = (const float*)d_in[1];
  const float* fWa = (const float*)d_in[2];
  const float* fba = (const float*)d_in[3];
  const float* fWb = (const float*)d_in[4];
  const float* fbb = (const float*)d_in[5];
  const float* fWc = (const float*)d_in[6];
  const float* fbc = (const float*)d_in[7];
  const float* W2a = (const float*)d_in[8];
  const float* b2a = (const float*)d_in[9];
  const float* W2b = (const float*)d_in[10];
  const float* b2b = (const float*)d_in[11];
  float* out = (float*)d_out;
  float* ws = (float*)d_ws;

  // carve (float units)
  float* wTa   = ws;                    // 2880
  float* BpAF  = wTa + 2880;            // 4096 halves = 2048 floats
  float* BpBF  = BpAF + 2048;           // 9216 halves = 4608 floats
  float* BpbF  = BpBF + 4608;           // 92160
  float* BpcF  = BpbF + 92160;          // 138240
  float* s1    = BpcF + 138240;         // 131072
  float* s2    = s1 + 131072;           // 32768
  float* s3    = s2 + 32768;            // 8192
  float* cat   = s3 + 8192;             // 2621440
  float* h2F   = cat + 2621440;         // 16777216
  float* fbF   = h2F + 16777216;        // 11534336
  _Float16* h2 = (_Float16*)h2F;
  _Float16* fb = (_Float16*)fbF;
  const half8* Bpb = (const half8*)BpbF;
  const half8* Bpc = (const half8*)BpcF;
  const half8* BpA = (const half8*)BpAF;
  const half8* BpB = (const half8*)BpBF;

  wtrans_kernel<<<dim3(3, 1, 5), 256, 0, stream>>>(fWa, wTa, 64, 1, 64, 576, 576);
  wpack_tail1_kernel<<<dim3(16, 1, 1), 256, 0, stream>>>(W2a, (_Float16*)BpAF);
  wpack_kernel<<<dim3(36, 1, 1), 256, 0, stream>>>(W2b, (_Float16*)BpBF, 1, 1, 0, 0);
  wpack_kernel<<<dim3(144, 1, 5), 256, 0, stream>>>(fWb, (_Float16*)BpbF, 64, 4, 36864, 36864);
  wpack_kernel<<<dim3(216, 1, 5), 256, 0, stream>>>(fWc, (_Float16*)BpcF, 81, 6, 46656, 55296);
  downsample_kernel<<<dim3(256, 1, 2), 256, 0, stream>>>(x, s1, 256, 256, 2, 512);
  downsample_kernel<<<dim3(64, 1, 2), 256, 0, stream>>>(x, s2, 128, 128, 4, 512);
  downsample_kernel<<<dim3(16, 1, 2), 256, 0, stream>>>(x, s3, 64, 64, 8, 512);

  const int HS_[5] = {512, 256, 128, 64, 512};
  const float* srcs[5] = {x, s1, s2, s3, g};
  const int strides[5] = {262144, 65536, 16384, 4096, 262144};
  for (int i = 0; i < 5; ++i) {
    const int Hs = HS_[i];
    conv12_mfma_kernel<<<dim3(Hs / 16, Hs / 16, 2), 256, 0, stream>>>(
        srcs[i], strides[i], wTa + i * 576, fba + i * 64,
        Bpb + (size_t)i * 4608, fbb + i * 64, h2, Hs, Hs);
    for (int n = 0; n < 2; ++n) {
      conv3x3_mfma_kernel<6, 81, 88, false, _Float16><<<dim3(Hs / 16, Hs / 16), 256, 0, stream>>>(
          h2 + (size_t)n * Hs * Hs * 64, Bpc + (size_t)i * 6912, fbc + i * 81, fb, Hs, Hs);
      const float* sn = srcs[i] + (size_t)n * strides[i];
      float* catn = cat + (size_t)n * 1310720;
      const int np = (Hs * Hs + 255) / 256;
      switch (i) {
        case 0: softdyn_kernel<1><<<np, 256, 0, stream>>>(fb, sn, catn, Hs, Hs, 0); break;
        case 1: softdyn_kernel<2><<<np, 256, 0, stream>>>(fb, sn, catn, Hs, Hs, 1); break;
        case 2: softdyn_kernel<4><<<np, 256, 0, stream>>>(fb, sn, catn, Hs, Hs, 2); break;
        case 3: softdyn_kernel<8><<<np, 256, 0, stream>>>(fb, sn, catn, Hs, Hs, 3); break;
        case 4: softdyn_kernel<1><<<np, 256, 0, stream>>>(fb, sn, catn, Hs, Hs, 4); break;
      }
    }
  }
  tail_fused_kernel<<<dim3(32, 32, 2), 256, 0, stream>>>(cat, BpA, b2a, BpB, b2b, out);
}

// Round 5
// 640.300 us; speedup vs baseline: 7.9100x; 1.3204x over previous
//
#include <hip/hip_runtime.h>
#include <math.h>

typedef _Float16 half8 __attribute__((ext_vector_type(8)));
typedef float f32x4 __attribute__((ext_vector_type(4)));

// ---------------- weight pack for MFMA (r2-verified layout) ----------------
// Bp[((s*NT+t)*64+lane)*8+j]: oc=t*16+(lane&15), tap=s>>1, ic=(s&1)*32+quad*8+j
__global__ void wpack_kernel(const float* __restrict__ src, _Float16* __restrict__ dst,
                             int COUT, int NT, int per_scale_src, int per_scale_dst) {
  const int sc = blockIdx.z;
  src += (size_t)sc * per_scale_src;
  dst += (size_t)sc * per_scale_dst;
  const int total = 18 * NT * 64 * 8;
  for (int idx = blockIdx.x * blockDim.x + threadIdx.x; idx < total;
       idx += gridDim.x * blockDim.x) {
    int j = idx & 7;
    int lane = (idx >> 3) & 63;
    int rest = idx >> 9;
    int t = rest % NT;
    int s = rest / NT;
    int oc = t * 16 + (lane & 15);
    int tap = s >> 1;
    int ic = (s & 1) * 32 + ((lane >> 4) & 3) * 8 + j;
    float v = (oc < COUT) ? src[((size_t)oc * 64 + ic) * 9 + tap] : 0.f;
    dst[idx] = (_Float16)v;
  }
}

// ---------------- pack conv1 weights (5,64,1,3,3): K=9 pad 32, 1 k-step, 4 nt ----------------
__global__ void wpack_conv1_kernel(const float* __restrict__ fWa, _Float16* __restrict__ dst) {
  int idx = blockIdx.x * blockDim.x + threadIdx.x;  // 2048 per scale
  int sc = blockIdx.z;
  if (idx >= 2048) return;
  int j = idx & 7, lane = (idx >> 3) & 63, nt = idx >> 9;
  int oc = nt * 16 + (lane & 15);
  int k = ((lane >> 4) & 3) * 8 + j;
  float v = (k < 9) ? fWa[sc * 576 + oc * 9 + k] : 0.f;
  dst[sc * 2048 + idx] = (_Float16)v;
}

// ---------------- pack W2a (64,5,3,3) for tail stage-1: K=45 pad 64, 2 k-steps, 4 n-tiles ----
__global__ void wpack_tail1_kernel(const float* __restrict__ W2a, _Float16* __restrict__ dst) {
  int idx = blockIdx.x * blockDim.x + threadIdx.x;  // 4096 total
  if (idx >= 4096) return;
  int j = idx & 7, lane = (idx >> 3) & 63;
  int nt = (idx >> 9) & 3, s = idx >> 11;
  int oc = nt * 16 + (lane & 15);
  int k = s * 32 + ((lane >> 4) & 3) * 8 + j;
  float v = 0.f;
  if (k < 45) {
    int ic = k / 9, tap = k - ic * 9;
    v = W2a[(oc * 5 + ic) * 9 + tap];
  }
  dst[idx] = (_Float16)v;
}

// ---------------- nearest downsample (C=1) ----------------
__global__ void downsample_kernel(const float* __restrict__ in, float* __restrict__ out,
                                  int Hs, int Ws, int r, int W) {
  const float* ip = in + (size_t)blockIdx.z * W * W;
  float* op = out + (size_t)blockIdx.z * Hs * Ws;
  int idx = blockIdx.x * blockDim.x + threadIdx.x;
  if (idx < Hs * Ws) {
    int rr = idx / Ws, cc = idx % Ws;
    op[idx] = ip[(size_t)(rr * r) * W + cc * r];
  }
}

// ---------------- shared MFMA K-loop over 18x18x64 swizzled slab (r2-verified) ----------------
template <int NT>
__device__ __forceinline__ void mfma_acc18(const _Float16* slab, const half8* __restrict__ Bp,
                                           f32x4 (&acc)[4][NT], int tid) {
  const int lane = tid & 63;
  const int wv = tid >> 6;
  const int quad = lane >> 4;
  const int ln15 = lane & 15;
  const f32x4 zz = {0.f, 0.f, 0.f, 0.f};
#pragma unroll
  for (int mt = 0; mt < 4; ++mt)
#pragma unroll
    for (int nt = 0; nt < NT; ++nt) acc[mt][nt] = zz;
#pragma unroll 1
  for (int s = 0; s < 18; ++s) {
    const int tap = s >> 1;
    const int dy = tap / 3;
    const int dx = tap - dy * 3;
    half8 bf[NT];
#pragma unroll
    for (int nt = 0; nt < NT; ++nt) bf[nt] = Bp[(s * NT + nt) * 64 + lane];
    const int C = dx + ln15;
    const int qsw = (((s & 1) * 4 + quad) ^ (C & 7));
    const _Float16* base = slab + C * 64 + qsw * 8;
    half8 af[4];
#pragma unroll
    for (int mt = 0; mt < 4; ++mt) {
      const int R = wv * 4 + mt + dy;
      af[mt] = *(const half8*)(base + R * (18 * 64));
    }
#pragma unroll
    for (int mt = 0; mt < 4; ++mt)
#pragma unroll
      for (int nt = 0; nt < NT; ++nt)
        acc[mt][nt] = __builtin_amdgcn_mfma_f32_16x16x32_f16(af[mt], bf[nt], acc[mt][nt], 0, 0, 0);
  }
}

// K-loop + store epilogue (r2-verified)
template <int NT, int COUT, int COUTP, bool RELU, typename OutT>
__device__ __forceinline__ void mfma_body(const _Float16* slab, const half8* __restrict__ Bp,
                                          const float* __restrict__ bias,
                                          OutT* __restrict__ out,
                                          int H, int W, int gr0, int gc0, int tid) {
  f32x4 acc[4][NT];
  mfma_acc18<NT>(slab, Bp, acc, tid);
  const int lane = tid & 63;
  const int wv = tid >> 6;
  const int quad = lane >> 4;
  const int ln15 = lane & 15;
#pragma unroll
  for (int nt = 0; nt < NT; ++nt) {
    const int oc = nt * 16 + ln15;
    const float bv = (oc < COUT) ? bias[oc] : 0.f;
#pragma unroll
    for (int mt = 0; mt < 4; ++mt) {
      const int gr = gr0 + wv * 4 + mt;
#pragma unroll
      for (int reg = 0; reg < 4; ++reg) {
        const int gc = gc0 + quad * 4 + reg;
        float v = acc[mt][nt][reg] + bv;
        if (RELU) v = fmaxf(v, 0.f);
        if (oc < COUTP) out[((size_t)gr * W + gc) * COUTP + oc] = (OutT)v;
      }
    }
  }
}

// ---------------- fused conv1(1->64,relu, MFMA) + conv2(64->64,relu, MFMA), z=batch ----------
__global__ __launch_bounds__(256)
void conv12_mfma_kernel(const float* __restrict__ x0, int srcStride,
                        const half8* __restrict__ Bp1,  // conv1 pack: 1 ks x 4 nt
                        const float* __restrict__ ba,   // [64]
                        const half8* __restrict__ Bp,   // conv2 pack: 18 ks x 4 nt
                        const float* __restrict__ bb,   // [64]
                        _Float16* __restrict__ out,     // h2, batch stride H*W*64
                        int H, int W) {
  __shared__ float xs[20 * 20];                         // first: gather clamps stay inside
  __shared__ __align__(16) _Float16 slab[18 * 18 * 64];
  const int n = blockIdx.z;
  const float* in = x0 + (size_t)n * srcStride;
  out += (size_t)n * H * W * 64;
  const int tid = threadIdx.x;
  const int gr0 = blockIdx.y * 16, gc0 = blockIdx.x * 16;
  for (int i = tid; i < 400; i += 256) {
    int R = i / 20, C = i % 20;
    int gr = gr0 - 2 + R, gc = gc0 - 2 + C;
    xs[i] = (gr >= 0 && gr < H && gc >= 0 && gc < W) ? in[(size_t)gr * W + gc] : 0.f;
  }
  __syncthreads();
  const int lane = tid & 63;
  const int wv = tid >> 6;
  const int quad = lane >> 4;
  const int ln15 = lane & 15;
  // conv1 via MFMA: M=324 halo px (21 m-tiles), K=9 pad 32, N=64
  half8 bf1[4];
  float bv1[4];
#pragma unroll
  for (int nt = 0; nt < 4; ++nt) {
    bf1[nt] = Bp1[nt * 64 + lane];
    bv1[nt] = ba[nt * 16 + ln15];
  }
  int off1[8];
  bool v1[8];
#pragma unroll
  for (int j = 0; j < 8; ++j) {
    int k = quad * 8 + j;
    v1[j] = (k < 9);
    off1[j] = v1[j] ? ((k / 3) * 20 + (k % 3)) : 0;
  }
  const f32x4 zz = {0.f, 0.f, 0.f, 0.f};
#pragma unroll 1
  for (int mt = wv; mt < 21; mt += 4) {
    int p = mt * 16 + ln15;
    int pcl = (p < 323) ? p : 323;
    int R = pcl / 18, C = pcl - R * 18;
    int base = R * 20 + C;
    half8 af;
#pragma unroll
    for (int j = 0; j < 8; ++j)
      af[j] = v1[j] ? (_Float16)xs[base + off1[j]] : (_Float16)0.f;
    f32x4 a1[4] = {zz, zz, zz, zz};
#pragma unroll
    for (int nt = 0; nt < 4; ++nt)
      a1[nt] = __builtin_amdgcn_mfma_f32_16x16x32_f16(af, bf1[nt], a1[nt], 0, 0, 0);
#pragma unroll
    for (int nt = 0; nt < 4; ++nt) {
      const int oc = nt * 16 + ln15;
#pragma unroll
      for (int reg = 0; reg < 4; ++reg) {
        int p2 = mt * 16 + quad * 4 + reg;
        if (p2 < 324) {
          int R2 = p2 / 18, C2 = p2 - R2 * 18;
          int gr = gr0 - 1 + R2, gc = gc0 - 1 + C2;
          float v = (gr >= 0 && gr < H && gc >= 0 && gc < W)
                        ? fmaxf(a1[nt][reg] + bv1[nt], 0.f) : 0.f;
          slab[p2 * 64 + (((oc >> 3) ^ (C2 & 7)) * 8) + (oc & 7)] = (_Float16)v;
        }
      }
    }
  }
  __syncthreads();
  mfma_body<4, 64, 64, true, _Float16>(slab, Bp, bb, out, H, W, gr0, gc0, tid);
}

// ---------------- fused conv3(64->81) + softmax(81) + 9x9 dynconv + upsample, z=batch -------
template <int RS>
__global__ __launch_bounds__(256)
void conv3sd_kernel(const _Float16* __restrict__ h2, const half8* __restrict__ Bp,
                    const float* __restrict__ bias, const float* __restrict__ s0,
                    float* __restrict__ cat, int H, int W, int sStride, int ch) {
  __shared__ __align__(16) _Float16 slab[18 * 18 * 64];
  __shared__ float xs[24 * 24];
  __shared__ float oarr[256];
  const int n = blockIdx.z;
  const _Float16* in = h2 + (size_t)n * H * W * 64;
  const float* s = s0 + (size_t)n * sStride;
  float* catn = cat + (size_t)n * (512 * 512 * 5);
  const int tid = threadIdx.x;
  const int gr0 = blockIdx.y * 16, gc0 = blockIdx.x * 16;
  for (int i = tid; i < 18 * 18 * 8; i += 256) {
    int chunk = i & 7, px = i >> 3;
    int R = px / 18, C = px % 18;
    int gr = gr0 - 1 + R, gc = gc0 - 1 + C;
    half8 v = {0, 0, 0, 0, 0, 0, 0, 0};
    if (gr >= 0 && gr < H && gc >= 0 && gc < W)
      v = *(const half8*)(in + ((size_t)gr * W + gc) * 64 + chunk * 8);
    *(half8*)(slab + px * 64 + (chunk ^ (C & 7)) * 8) = v;
  }
  for (int i = tid; i < 576; i += 256) {
    int R = i / 24, C = i % 24;
    int gr = gr0 - 4 + R, gc = gc0 - 4 + C;
    xs[i] = (gr >= 0 && gr < H && gc >= 0 && gc < W) ? s[(size_t)gr * W + gc] : 0.f;
  }
  __syncthreads();
  f32x4 acc[4][6];
  mfma_acc18<6>(slab, Bp, acc, tid);
  const int lane = tid & 63;
  const int wv = tid >> 6;
  const int quad = lane >> 4;
  const int ln15 = lane & 15;
  // per-lane channel meta: oc = nt*16+ln15; tap (dy,dx) = (oc/9, oc%9)
  float bv[6];
  int dyx[6];
  bool val[6];
#pragma unroll
  for (int nt = 0; nt < 6; ++nt) {
    int oc = nt * 16 + ln15;
    val[nt] = (oc < 81);
    bv[nt] = val[nt] ? bias[oc] : 0.f;
    int dy = oc / 9, dx = oc - dy * 9;
    dyx[nt] = val[nt] ? dy * 24 + dx : 0;
  }
  // pixel (row=wv*4+mt, col=quad*4+reg); its 96 channels live in the 16 lanes of this quad
#pragma unroll
  for (int mt = 0; mt < 4; ++mt) {
    const int pr = wv * 4 + mt;
#pragma unroll
    for (int reg = 0; reg < 4; ++reg) {
      const int pc = quad * 4 + reg;
      const int base = pr * 24 + pc;
      float sum = 0.f, y = 0.f;
#pragma unroll
      for (int nt = 0; nt < 6; ++nt) {
        float e = val[nt] ? __expf(acc[mt][nt][reg] + bv[nt]) : 0.f;
        sum += e;
        y = fmaf(e, xs[base + dyx[nt]], y);
      }
#pragma unroll
      for (int m = 1; m < 16; m <<= 1) {
        sum += __shfl_xor(sum, m, 64);
        y   += __shfl_xor(y, m, 64);
      }
      if (ln15 == 0) oarr[pr * 16 + pc] = y / sum;
    }
  }
  __syncthreads();
  const int r = tid >> 4, c = tid & 15;
  const float o = oarr[tid];
  const int R0 = (gr0 + r) * RS, C0 = (gc0 + c) * RS;
#pragma unroll
  for (int a = 0; a < RS; ++a)
#pragma unroll
    for (int b = 0; b < RS; ++b)
      catn[((size_t)(R0 + a) * 512 + (C0 + b)) * 5 + ch] = o;
}

// ---------------- fused tail: cat(5) -> MFMA 5->64 relu (LDS) -> MFMA 64->1 ----------------
__global__ __launch_bounds__(256)
void tail_fused_kernel(const float* __restrict__ cat,
                       const half8* __restrict__ BpA,   // stage1 pack: 2 ks x 4 nt
                       const float* __restrict__ b2a,   // [64]
                       const half8* __restrict__ BpB,   // stage2 pack: 18 ks x 1 nt
                       const float* __restrict__ b2b,
                       float* __restrict__ out) {
  __shared__ float cs[20 * 20 * 5];                      // first: gather clamps stay inside
  __shared__ __align__(16) _Float16 hid[18 * 18 * 64];
  const int n = blockIdx.z;
  const float* cin = cat + (size_t)n * (512 * 512 * 5);
  float* op = out + (size_t)n * (512 * 512);
  const int tid = threadIdx.x;
  const int gr0 = blockIdx.y * 16, gc0 = blockIdx.x * 16;
  for (int i = tid; i < 2000; i += 256) {
    int px = i / 5, ic = i - px * 5;
    int R = px / 20, C = px - R * 20;
    int gr = gr0 - 2 + R, gc = gc0 - 2 + C;
    cs[i] = (gr >= 0 && gr < 512 && gc >= 0 && gc < 512)
                ? cin[((size_t)gr * 512 + gc) * 5 + ic] : 0.f;
  }
  __syncthreads();
  const int lane = tid & 63;
  const int wv = tid >> 6;
  const int quad = lane >> 4;
  const int ln15 = lane & 15;
  int goff[2][8];
  bool gok[2][8];
#pragma unroll
  for (int s = 0; s < 2; ++s)
#pragma unroll
    for (int j = 0; j < 8; ++j) {
      int k = s * 32 + quad * 8 + j;
      bool ok = (k < 45);
      int ic = k / 9;
      int tap = k - ic * 9;
      int dy = tap / 3, dx = tap - dy * 3;
      goff[s][j] = ok ? ((dy * 20 + dx) * 5 + ic) : 0;
      gok[s][j] = ok;
    }
  half8 bfA[2][4];
#pragma unroll
  for (int s = 0; s < 2; ++s)
#pragma unroll
    for (int nt = 0; nt < 4; ++nt) bfA[s][nt] = BpA[(s * 4 + nt) * 64 + lane];
  float bvA[4];
#pragma unroll
  for (int nt = 0; nt < 4; ++nt) bvA[nt] = b2a[nt * 16 + ln15];
  const f32x4 zz = {0.f, 0.f, 0.f, 0.f};
#pragma unroll 1
  for (int mt = wv; mt < 21; mt += 4) {
    int px = mt * 16 + ln15;
    int pc = (px < 323) ? px : 323;
    int base = (pc / 18) * 100 + (pc % 18) * 5;  // (R*20+C)*5
    f32x4 acc1[4] = {zz, zz, zz, zz};
#pragma unroll
    for (int s = 0; s < 2; ++s) {
      half8 af;
#pragma unroll
      for (int j = 0; j < 8; ++j) {
        float a = gok[s][j] ? cs[base + goff[s][j]] : 0.f;
        af[j] = (_Float16)a;
      }
#pragma unroll
      for (int nt = 0; nt < 4; ++nt)
        acc1[nt] = __builtin_amdgcn_mfma_f32_16x16x32_f16(af, bfA[s][nt], acc1[nt], 0, 0, 0);
    }
#pragma unroll
    for (int nt = 0; nt < 4; ++nt) {
      const int oc = nt * 16 + ln15;
#pragma unroll
      for (int reg = 0; reg < 4; ++reg) {
        int p2 = mt * 16 + quad * 4 + reg;
        if (p2 < 324) {
          int R = p2 / 18, C = p2 - R * 18;
          int gr = gr0 - 1 + R, gc = gc0 - 1 + C;
          float v = (gr >= 0 && gr < 512 && gc >= 0 && gc < 512)
                        ? fmaxf(acc1[nt][reg] + bvA[nt], 0.f) : 0.f;
          hid[p2 * 64 + (((oc >> 3) ^ (C & 7)) * 8) + (oc & 7)] = (_Float16)v;
        }
      }
    }
  }
  __syncthreads();
  mfma_body<1, 1, 1, false, float>(hid, BpB, b2b, op, 512, 512, gr0, gc0, tid);
}

extern "C" void kernel_launch(void* const* d_in, const int* in_sizes, int n_in,
                              void* d_out, int out_size, void* d_ws, size_t ws_size,
                              hipStream_t stream) {
  (void)in_sizes; (void)n_in; (void)out_size; (void)ws_size;
  const float* x   = (const float*)d_in[0];
  const float* g   = (const float*)d_in[1];
  const float* fWa = (const float*)d_in[2];
  const float* fba = (const float*)d_in[3];
  const float* fWb = (const float*)d_in[4];
  const float* fbb = (const float*)d_in[5];
  const float* fWc = (const float*)d_in[6];
  const float* fbc = (const float*)d_in[7];
  const float* W2a = (const float*)d_in[8];
  const float* b2a = (const float*)d_in[9];
  const float* W2b = (const float*)d_in[10];
  const float* b2b = (const float*)d_in[11];
  float* out = (float*)d_out;
  float* ws = (float*)d_ws;

  // carve (float units), total ~19.8M floats = 79 MB
  float* Bp1F  = ws;                    // 5*2048 halves = 5120 floats
  float* BpAF  = Bp1F + 5120;           // 2048
  float* BpBF  = BpAF + 2048;           // 4608
  float* BpbF  = BpBF + 4608;           // 92160
  float* BpcF  = BpbF + 92160;          // 138240
  float* s1    = BpcF + 138240;         // 131072
  float* s2    = s1 + 131072;           // 32768
  float* s3    = s2 + 32768;            // 8192
  float* cat   = s3 + 8192;             // 2621440
  float* h2F   = cat + 2621440;         // 2*512^2*64 halves = 16777216 floats
  _Float16* h2 = (_Float16*)h2F;
  const half8* Bp1 = (const half8*)Bp1F;   // 256 half8 per scale
  const half8* BpA = (const half8*)BpAF;
  const half8* BpB = (const half8*)BpBF;
  const half8* Bpb = (const half8*)BpbF;   // 4608 half8 per scale
  const half8* Bpc = (const half8*)BpcF;   // 6912 half8 per scale

  wpack_conv1_kernel<<<dim3(8, 1, 5), 256, 0, stream>>>(fWa, (_Float16*)Bp1F);
  wpack_tail1_kernel<<<dim3(16, 1, 1), 256, 0, stream>>>(W2a, (_Float16*)BpAF);
  wpack_kernel<<<dim3(36, 1, 1), 256, 0, stream>>>(W2b, (_Float16*)BpBF, 1, 1, 0, 0);
  wpack_kernel<<<dim3(144, 1, 5), 256, 0, stream>>>(fWb, (_Float16*)BpbF, 64, 4, 36864, 36864);
  wpack_kernel<<<dim3(216, 1, 5), 256, 0, stream>>>(fWc, (_Float16*)BpcF, 81, 6, 46656, 55296);
  downsample_kernel<<<dim3(256, 1, 2), 256, 0, stream>>>(x, s1, 256, 256, 2, 512);
  downsample_kernel<<<dim3(64, 1, 2), 256, 0, stream>>>(x, s2, 128, 128, 4, 512);
  downsample_kernel<<<dim3(16, 1, 2), 256, 0, stream>>>(x, s3, 64, 64, 8, 512);

  const int HS_[5] = {512, 256, 128, 64, 512};
  const float* srcs[5] = {x, s1, s2, s3, g};
  const int strides[5] = {262144, 65536, 16384, 4096, 262144};
  for (int i = 0; i < 5; ++i) {
    const int Hs = HS_[i];
    dim3 grid(Hs / 16, Hs / 16, 2);
    conv12_mfma_kernel<<<grid, 256, 0, stream>>>(
        srcs[i], strides[i], Bp1 + (size_t)i * 256, fba + i * 64,
        Bpb + (size_t)i * 4608, fbb + i * 64, h2, Hs, Hs);
    switch (i) {
      case 0: conv3sd_kernel<1><<<grid, 256, 0, stream>>>(
                  h2, Bpc + (size_t)i * 6912, fbc + i * 81, srcs[i], cat, Hs, Hs, strides[i], i); break;
      case 1: conv3sd_kernel<2><<<grid, 256, 0, stream>>>(
                  h2, Bpc + (size_t)i * 6912, fbc + i * 81, srcs[i], cat, Hs, Hs, strides[i], i); break;
      case 2: conv3sd_kernel<4><<<grid, 256, 0, stream>>>(
                  h2, Bpc + (size_t)i * 6912, fbc + i * 81, srcs[i], cat, Hs, Hs, strides[i], i); break;
      case 3: conv3sd_kernel<8><<<grid, 256, 0, stream>>>(
                  h2, Bpc + (size_t)i * 6912, fbc + i * 81, srcs[i], cat, Hs, Hs, strides[i], i); break;
      case 4: conv3sd_kernel<1><<<grid, 256, 0, stream>>>(
                  h2, Bpc + (size_t)i * 6912, fbc + i * 81, srcs[i], cat, Hs, Hs, strides[i], i); break;
    }
  }
  tail_fused_kernel<<<dim3(32, 32, 2), 256, 0, stream>>>(cat, BpA, b2a, BpB, b2b, out);
}

// Round 6
// 613.813 us; speedup vs baseline: 8.2514x; 1.0432x over previous
//
#include <hip/hip_runtime.h>
#include <math.h>

typedef _Float16 half8 __attribute__((ext_vector_type(8)));
typedef float f32x4 __attribute__((ext_vector_type(4)));

// ---------------- merged weight-pack kernel (all 5 packs, r2-verified layouts) -------------
__device__ __forceinline__ void pack_generic(int rem, int NT, int COUT,
                                             const float* __restrict__ src,
                                             _Float16* __restrict__ dst) {
  int j = rem & 7, lane = (rem >> 3) & 63, rest = rem >> 9;
  int t = rest % NT, s = rest / NT;
  int oc = t * 16 + (lane & 15);
  int tap = s >> 1;
  int ic = (s & 1) * 32 + ((lane >> 4) & 3) * 8 + j;
  float v = (oc < COUT) ? src[((size_t)oc * 64 + ic) * 9 + tap] : 0.f;
  dst[rem] = (_Float16)v;
}

__global__ void pack_all_kernel(const float* __restrict__ fWa, const float* __restrict__ fWb,
                                const float* __restrict__ fWc, const float* __restrict__ W2a,
                                const float* __restrict__ W2b,
                                _Float16* __restrict__ Bp1, _Float16* __restrict__ BpA,
                                _Float16* __restrict__ BpB, _Float16* __restrict__ Bpb,
                                _Float16* __restrict__ Bpc) {
  int idx = blockIdx.x * blockDim.x + threadIdx.x;
  if (idx < 184320) {                       // Bpb: 5 scales x 18x4x512
    int sc = idx / 36864, rem = idx - sc * 36864;
    pack_generic(rem, 4, 64, fWb + sc * 36864, Bpb + sc * 36864);
  } else if (idx < 460800) {                // Bpc: 5 scales x 18x6x512
    int i2 = idx - 184320;
    int sc = i2 / 55296, rem = i2 - sc * 55296;
    pack_generic(rem, 6, 81, fWc + sc * 46656, Bpc + sc * 55296);
  } else if (idx < 471040) {                // Bp1: conv1, K=9 pad 32
    int i2 = idx - 460800;
    int sc = i2 >> 11, rem = i2 & 2047;
    int j = rem & 7, lane = (rem >> 3) & 63, nt = rem >> 9;
    int oc = nt * 16 + (lane & 15);
    int k = ((lane >> 4) & 3) * 8 + j;
    float v = (k < 9) ? fWa[sc * 576 + oc * 9 + k] : 0.f;
    Bp1[sc * 2048 + rem] = (_Float16)v;
  } else if (idx < 475136) {                // BpA: tail stage1, K=45 pad 64
    int rem = idx - 471040;
    int j = rem & 7, lane = (rem >> 3) & 63;
    int nt = (rem >> 9) & 3, s = rem >> 11;
    int oc = nt * 16 + (lane & 15);
    int k = s * 32 + ((lane >> 4) & 3) * 8 + j;
    float v = 0.f;
    if (k < 45) { int ic = k / 9, tap = k - ic * 9; v = W2a[(oc * 5 + ic) * 9 + tap]; }
    BpA[rem] = (_Float16)v;
  } else if (idx < 484352) {                // BpB: tail stage2 (COUT=1, NT=1)
    pack_generic(idx - 475136, 1, 1, W2b, BpB);
  }
}

// ---------------- merged nearest downsample (s1,s2,s3 both batches) ----------------
__global__ void down_all_kernel(const float* __restrict__ x, float* __restrict__ s1,
                                float* __restrict__ s2, float* __restrict__ s3) {
  int idx = blockIdx.x * blockDim.x + threadIdx.x;
  if (idx < 131072) {
    int n = idx >> 16, p = idx & 65535, rr = p >> 8, cc = p & 255;
    s1[idx] = x[(size_t)n * 262144 + (size_t)(rr * 2) * 512 + cc * 2];
  } else if (idx < 163840) {
    int i2 = idx - 131072;
    int n = i2 >> 14, p = i2 & 16383, rr = p >> 7, cc = p & 127;
    s2[i2] = x[(size_t)n * 262144 + (size_t)(rr * 4) * 512 + cc * 4];
  } else if (idx < 172032) {
    int i2 = idx - 163840;
    int n = i2 >> 12, p = i2 & 4095, rr = p >> 6, cc = p & 63;
    s3[i2] = x[(size_t)n * 262144 + (size_t)(rr * 8) * 512 + cc * 8];
  }
}

// ---------------- block -> (scale, batch, tile) mapping, compile-time groups --------------
// GROUP 0: scales {0 (x,512), 4 (g,512)}; GROUP 1: {1 (256), 2 (128), 3 (64)}
template <int GROUP>
__device__ __forceinline__ void map_block(int bid, int& sc, int& n, int& bx, int& by,
                                          int& Hs, int& RS, int& h2off) {
  if (GROUP == 0) {
    if (bid < 2048) { sc = 0; Hs = 512; RS = 1; h2off = 0;
      int t = bid; n = t >> 10; t &= 1023; by = t >> 5; bx = t & 31; }
    else { sc = 4; Hs = 512; RS = 1; h2off = 33554432;
      int t = bid - 2048; n = t >> 10; t &= 1023; by = t >> 5; bx = t & 31; }
  } else {
    if (bid < 512) { sc = 1; Hs = 256; RS = 2; h2off = 0;
      int t = bid; n = t >> 8; t &= 255; by = t >> 4; bx = t & 15; }
    else if (bid < 640) { sc = 2; Hs = 128; RS = 4; h2off = 8388608;
      int t = bid - 512; n = t >> 6; t &= 63; by = t >> 3; bx = t & 7; }
    else { sc = 3; Hs = 64; RS = 8; h2off = 10485760;
      int t = bid - 640; n = t >> 4; t &= 15; by = t >> 2; bx = t & 3; }
  }
}

__device__ __forceinline__ const float* pick_src(int sc, const float* x, const float* g,
                                                 const float* s1, const float* s2,
                                                 const float* s3, int& sStr) {
  if (sc == 0) { sStr = 262144; return x; }
  if (sc == 1) { sStr = 65536; return s1; }
  if (sc == 2) { sStr = 16384; return s2; }
  if (sc == 3) { sStr = 4096; return s3; }
  sStr = 262144; return g;
}

// ---------------- shared MFMA K-loop over 18x18x64 swizzled slab (r2-verified) -------------
template <int NT>
__device__ __forceinline__ void mfma_acc18(const _Float16* slab, const half8* __restrict__ Bp,
                                           f32x4 (&acc)[4][NT], int tid) {
  const int lane = tid & 63;
  const int wv = tid >> 6;
  const int quad = lane >> 4;
  const int ln15 = lane & 15;
  const f32x4 zz = {0.f, 0.f, 0.f, 0.f};
#pragma unroll
  for (int mt = 0; mt < 4; ++mt)
#pragma unroll
    for (int nt = 0; nt < NT; ++nt) acc[mt][nt] = zz;
#pragma unroll 1
  for (int s = 0; s < 18; ++s) {
    const int tap = s >> 1;
    const int dy = tap / 3;
    const int dx = tap - dy * 3;
    half8 bf[NT];
#pragma unroll
    for (int nt = 0; nt < NT; ++nt) bf[nt] = Bp[(s * NT + nt) * 64 + lane];
    const int C = dx + ln15;
    const int qsw = (((s & 1) * 4 + quad) ^ (C & 7));
    const _Float16* base = slab + C * 64 + qsw * 8;
    half8 af[4];
#pragma unroll
    for (int mt = 0; mt < 4; ++mt) {
      const int R = wv * 4 + mt + dy;
      af[mt] = *(const half8*)(base + R * (18 * 64));
    }
#pragma unroll
    for (int mt = 0; mt < 4; ++mt)
#pragma unroll
      for (int nt = 0; nt < NT; ++nt)
        acc[mt][nt] = __builtin_amdgcn_mfma_f32_16x16x32_f16(af[mt], bf[nt], acc[mt][nt], 0, 0, 0);
  }
}

template <int NT, int COUT, int COUTP, bool RELU, typename OutT>
__device__ __forceinline__ void mfma_body(const _Float16* slab, const half8* __restrict__ Bp,
                                          const float* __restrict__ bias,
                                          OutT* __restrict__ out,
                                          int H, int W, int gr0, int gc0, int tid) {
  f32x4 acc[4][NT];
  mfma_acc18<NT>(slab, Bp, acc, tid);
  const int lane = tid & 63;
  const int wv = tid >> 6;
  const int quad = lane >> 4;
  const int ln15 = lane & 15;
#pragma unroll
  for (int nt = 0; nt < NT; ++nt) {
    const int oc = nt * 16 + ln15;
    const float bv = (oc < COUT) ? bias[oc] : 0.f;
#pragma unroll
    for (int mt = 0; mt < 4; ++mt) {
      const int gr = gr0 + wv * 4 + mt;
#pragma unroll
      for (int reg = 0; reg < 4; ++reg) {
        const int gc = gc0 + quad * 4 + reg;
        float v = acc[mt][nt][reg] + bv;
        if (RELU) v = fmaxf(v, 0.f);
        if (oc < COUTP) out[((size_t)gr * W + gc) * COUTP + oc] = (OutT)v;
      }
    }
  }
}

// ---------------- multi-scale fused conv1+conv2 (MFMA), one dispatch per group ------------
template <int GROUP>
__global__ __launch_bounds__(256)
void conv12_ms_kernel(const float* __restrict__ x, const float* __restrict__ g,
                      const float* __restrict__ s1, const float* __restrict__ s2,
                      const float* __restrict__ s3,
                      const half8* __restrict__ Bp1b, const float* __restrict__ fba,
                      const half8* __restrict__ Bpbb, const float* __restrict__ fbb,
                      _Float16* __restrict__ h2) {
  __shared__ float xs[20 * 20];                         // first: gather clamps stay inside
  __shared__ __align__(16) _Float16 slab[18 * 18 * 64];
  int sc, n, bx, by, Hs, RS, h2off;
  map_block<GROUP>(blockIdx.x, sc, n, bx, by, Hs, RS, h2off);
  int sStr;
  const float* src = pick_src(sc, x, g, s1, s2, s3, sStr);
  const float* in = src + (size_t)n * sStr;
  _Float16* out = h2 + h2off + (size_t)n * Hs * Hs * 64;
  const half8* Bp1 = Bp1b + sc * 256;
  const half8* Bp = Bpbb + sc * 4608;
  const float* ba = fba + sc * 64;
  const float* bb = fbb + sc * 64;
  const int H = Hs, W = Hs;
  const int tid = threadIdx.x;
  const int gr0 = by * 16, gc0 = bx * 16;
  for (int i = tid; i < 400; i += 256) {
    int R = i / 20, C = i % 20;
    int gr = gr0 - 2 + R, gc = gc0 - 2 + C;
    xs[i] = (gr >= 0 && gr < H && gc >= 0 && gc < W) ? in[(size_t)gr * W + gc] : 0.f;
  }
  __syncthreads();
  const int lane = tid & 63;
  const int wv = tid >> 6;
  const int quad = lane >> 4;
  const int ln15 = lane & 15;
  half8 bf1[4];
  float bv1[4];
#pragma unroll
  for (int nt = 0; nt < 4; ++nt) {
    bf1[nt] = Bp1[nt * 64 + lane];
    bv1[nt] = ba[nt * 16 + ln15];
  }
  int off1[8];
  bool v1[8];
#pragma unroll
  for (int j = 0; j < 8; ++j) {
    int k = quad * 8 + j;
    v1[j] = (k < 9);
    off1[j] = v1[j] ? ((k / 3) * 20 + (k % 3)) : 0;
  }
  const f32x4 zz = {0.f, 0.f, 0.f, 0.f};
#pragma unroll 1
  for (int mt = wv; mt < 21; mt += 4) {
    int p = mt * 16 + ln15;
    int pcl = (p < 323) ? p : 323;
    int R = pcl / 18, C = pcl - R * 18;
    int base = R * 20 + C;
    half8 af;
#pragma unroll
    for (int j = 0; j < 8; ++j)
      af[j] = v1[j] ? (_Float16)xs[base + off1[j]] : (_Float16)0.f;
    f32x4 a1[4] = {zz, zz, zz, zz};
#pragma unroll
    for (int nt = 0; nt < 4; ++nt)
      a1[nt] = __builtin_amdgcn_mfma_f32_16x16x32_f16(af, bf1[nt], a1[nt], 0, 0, 0);
#pragma unroll
    for (int nt = 0; nt < 4; ++nt) {
      const int oc = nt * 16 + ln15;
#pragma unroll
      for (int reg = 0; reg < 4; ++reg) {
        int p2 = mt * 16 + quad * 4 + reg;
        if (p2 < 324) {
          int R2 = p2 / 18, C2 = p2 - R2 * 18;
          int gr = gr0 - 1 + R2, gc = gc0 - 1 + C2;
          float v = (gr >= 0 && gr < H && gc >= 0 && gc < W)
                        ? fmaxf(a1[nt][reg] + bv1[nt], 0.f) : 0.f;
          slab[p2 * 64 + (((oc >> 3) ^ (C2 & 7)) * 8) + (oc & 7)] = (_Float16)v;
        }
      }
    }
  }
  __syncthreads();
  mfma_body<4, 64, 64, true, _Float16>(slab, Bp, bb, out, H, W, gr0, gc0, tid);
}

// ---------------- multi-scale fused conv3 + softmax + dynconv + upsample ------------------
// After K-loop, f goes to LDS (chunk-XOR swizzle) and each thread owns one pixel:
// 12 ds_read_b128 + 81 exp + 81 xs gathers, no cross-lane reductions.
template <int GROUP>
__global__ __launch_bounds__(256)
void conv3sd_ms_kernel(const _Float16* __restrict__ h2, const half8* __restrict__ Bpcb,
                       const float* __restrict__ fbc,
                       const float* __restrict__ x, const float* __restrict__ g,
                       const float* __restrict__ s1, const float* __restrict__ s2,
                       const float* __restrict__ s3, float* __restrict__ cat) {
  __shared__ __align__(16) _Float16 ubuf[256 * 96];    // 49152 B: slab (20736 used) / ftile
  __shared__ float xs[24 * 24];
  int sc, n, bx, by, Hs, RS, h2off;
  map_block<GROUP>(blockIdx.x, sc, n, bx, by, Hs, RS, h2off);
  int sStr;
  const float* src = pick_src(sc, x, g, s1, s2, s3, sStr);
  const float* s = src + (size_t)n * sStr;
  const _Float16* in = h2 + h2off + (size_t)n * Hs * Hs * 64;
  const half8* Bp = Bpcb + sc * 6912;
  const float* bias = fbc + sc * 81;
  float* catn = cat + (size_t)n * 1310720;
  const int H = Hs, W = Hs;
  const int tid = threadIdx.x;
  const int gr0 = by * 16, gc0 = bx * 16;
  for (int i = tid; i < 18 * 18 * 8; i += 256) {
    int chunk = i & 7, px = i >> 3;
    int R = px / 18, C = px % 18;
    int gr = gr0 - 1 + R, gc = gc0 - 1 + C;
    half8 v = {0, 0, 0, 0, 0, 0, 0, 0};
    if (gr >= 0 && gr < H && gc >= 0 && gc < W)
      v = *(const half8*)(in + ((size_t)gr * W + gc) * 64 + chunk * 8);
    *(half8*)(ubuf + px * 64 + (chunk ^ (C & 7)) * 8) = v;
  }
  for (int i = tid; i < 576; i += 256) {
    int R = i / 24, C = i % 24;
    int gr = gr0 - 4 + R, gc = gc0 - 4 + C;
    xs[i] = (gr >= 0 && gr < H && gc >= 0 && gc < W) ? s[(size_t)gr * W + gc] : 0.f;
  }
  __syncthreads();
  f32x4 acc[4][6];
  mfma_acc18<6>(ubuf, Bp, acc, tid);
  __syncthreads();                                      // done reading slab
  const int lane = tid & 63;
  const int wv = tid >> 6;
  const int quad = lane >> 4;
  const int ln15 = lane & 15;
  float bv[6];
#pragma unroll
  for (int nt = 0; nt < 6; ++nt) {
    int ch = nt * 16 + ln15;
    bv[nt] = (ch < 81) ? bias[ch] : 0.f;
  }
  // store f -> ftile[px][96], chunk' = chunk ^ ((px>>2)&3)
#pragma unroll
  for (int mt = 0; mt < 4; ++mt) {
#pragma unroll
    for (int nt = 0; nt < 6; ++nt) {
      const int ch = nt * 16 + ln15;
#pragma unroll
      for (int reg = 0; reg < 4; ++reg) {
        const int px = (wv * 4 + mt) * 16 + quad * 4 + reg;
        ubuf[px * 96 + (((ch >> 3) ^ ((px >> 2) & 3)) << 3) + (ch & 7)] =
            (_Float16)(acc[mt][nt][reg] + bv[nt]);
      }
    }
  }
  __syncthreads();
  // per-thread softmax + dynamic conv
  const int px = tid;
  const int sw = (px >> 2) & 3;
  const _Float16* frow = ubuf + px * 96;
  const float* xb = xs + (px >> 4) * 24 + (px & 15);
  float sum = 0.f, y = 0.f;
#pragma unroll
  for (int c12 = 0; c12 < 11; ++c12) {
    half8 h = *(const half8*)(frow + ((c12 ^ sw) << 3));
#pragma unroll
    for (int j = 0; j < 8; ++j) {
      const int ch = c12 * 8 + j;
      if (ch >= 81) break;
      float e = __expf((float)h[j]);
      const int dy = ch / 9, dx = ch - dy * 9;
      sum += e;
      y = fmaf(e, xb[dy * 24 + dx], y);
    }
  }
  const float o = y / sum;
  const int gr = gr0 + (px >> 4), gc = gc0 + (px & 15);
  for (int a = 0; a < RS; ++a)
    for (int b = 0; b < RS; ++b)
      catn[((size_t)(gr * RS + a) * 512 + (gc * RS + b)) * 5 + sc] = o;
}

// ---------------- fused tail: cat(5) -> MFMA 5->64 relu (LDS) -> MFMA 64->1 ----------------
__global__ __launch_bounds__(256)
void tail_fused_kernel(const float* __restrict__ cat,
                       const half8* __restrict__ BpA, const float* __restrict__ b2a,
                       const half8* __restrict__ BpB, const float* __restrict__ b2b,
                       float* __restrict__ out) {
  __shared__ float cs[20 * 20 * 5];                      // first: gather clamps stay inside
  __shared__ __align__(16) _Float16 hid[18 * 18 * 64];
  const int n = blockIdx.z;
  const float* cin = cat + (size_t)n * (512 * 512 * 5);
  float* op = out + (size_t)n * (512 * 512);
  const int tid = threadIdx.x;
  const int gr0 = blockIdx.y * 16, gc0 = blockIdx.x * 16;
  for (int i = tid; i < 2000; i += 256) {
    int px = i / 5, ic = i - px * 5;
    int R = px / 20, C = px - R * 20;
    int gr = gr0 - 2 + R, gc = gc0 - 2 + C;
    cs[i] = (gr >= 0 && gr < 512 && gc >= 0 && gc < 512)
                ? cin[((size_t)gr * 512 + gc) * 5 + ic] : 0.f;
  }
  __syncthreads();
  const int lane = tid & 63;
  const int wv = tid >> 6;
  const int quad = lane >> 4;
  const int ln15 = lane & 15;
  int goff[2][8];
  bool gok[2][8];
#pragma unroll
  for (int s = 0; s < 2; ++s)
#pragma unroll
    for (int j = 0; j < 8; ++j) {
      int k = s * 32 + quad * 8 + j;
      bool ok = (k < 45);
      int ic = k / 9;
      int tap = k - ic * 9;
      int dy = tap / 3, dx = tap - dy * 3;
      goff[s][j] = ok ? ((dy * 20 + dx) * 5 + ic) : 0;
      gok[s][j] = ok;
    }
  half8 bfA[2][4];
#pragma unroll
  for (int s = 0; s < 2; ++s)
#pragma unroll
    for (int nt = 0; nt < 4; ++nt) bfA[s][nt] = BpA[(s * 4 + nt) * 64 + lane];
  float bvA[4];
#pragma unroll
  for (int nt = 0; nt < 4; ++nt) bvA[nt] = b2a[nt * 16 + ln15];
  const f32x4 zz = {0.f, 0.f, 0.f, 0.f};
#pragma unroll 1
  for (int mt = wv; mt < 21; mt += 4) {
    int px = mt * 16 + ln15;
    int pc = (px < 323) ? px : 323;
    int base = (pc / 18) * 100 + (pc % 18) * 5;
    f32x4 acc1[4] = {zz, zz, zz, zz};
#pragma unroll
    for (int s = 0; s < 2; ++s) {
      half8 af;
#pragma unroll
      for (int j = 0; j < 8; ++j) {
        float a = gok[s][j] ? cs[base + goff[s][j]] : 0.f;
        af[j] = (_Float16)a;
      }
#pragma unroll
      for (int nt = 0; nt < 4; ++nt)
        acc1[nt] = __builtin_amdgcn_mfma_f32_16x16x32_f16(af, bfA[s][nt], acc1[nt], 0, 0, 0);
    }
#pragma unroll
    for (int nt = 0; nt < 4; ++nt) {
      const int oc = nt * 16 + ln15;
#pragma unroll
      for (int reg = 0; reg < 4; ++reg) {
        int p2 = mt * 16 + quad * 4 + reg;
        if (p2 < 324) {
          int R = p2 / 18, C = p2 - R * 18;
          int gr = gr0 - 1 + R, gc = gc0 - 1 + C;
          float v = (gr >= 0 && gr < 512 && gc >= 0 && gc < 512)
                        ? fmaxf(acc1[nt][reg] + bvA[nt], 0.f) : 0.f;
          hid[p2 * 64 + (((oc >> 3) ^ (C & 7)) * 8) + (oc & 7)] = (_Float16)v;
        }
      }
    }
  }
  __syncthreads();
  mfma_body<1, 1, 1, false, float>(hid, BpB, b2b, op, 512, 512, gr0, gc0, tid);
}

extern "C" void kernel_launch(void* const* d_in, const int* in_sizes, int n_in,
                              void* d_out, int out_size, void* d_ws, size_t ws_size,
                              hipStream_t stream) {
  (void)in_sizes; (void)n_in; (void)out_size; (void)ws_size;
  const float* x   = (const float*)d_in[0];
  const float* g   = (const float*)d_in[1];
  const float* fWa = (const float*)d_in[2];
  const float* fba = (const float*)d_in[3];
  const float* fWb = (const float*)d_in[4];
  const float* fbb = (const float*)d_in[5];
  const float* fWc = (const float*)d_in[6];
  const float* fbc = (const float*)d_in[7];
  const float* W2a = (const float*)d_in[8];
  const float* b2a = (const float*)d_in[9];
  const float* W2b = (const float*)d_in[10];
  const float* b2b = (const float*)d_in[11];
  float* out = (float*)d_out;
  float* ws = (float*)d_ws;

  // carve (float units), total ~36.6M floats = 146 MB
  float* Bp1F = ws;                     // 10240 halves = 5120 floats
  float* BpAF = Bp1F + 5120;            // 2048
  float* BpBF = BpAF + 2048;            // 4608
  float* BpbF = BpBF + 4608;            // 92160
  float* BpcF = BpbF + 92160;           // 138240
  float* s1   = BpcF + 138240;          // 131072
  float* s2   = s1 + 131072;            // 32768
  float* s3   = s2 + 32768;             // 8192
  float* cat  = s3 + 8192;              // 2621440
  float* h2F  = cat + 2621440;          // 67108864 halves = 33554432 floats
  _Float16* h2 = (_Float16*)h2F;
  const half8* Bp1 = (const half8*)Bp1F;
  const half8* BpA = (const half8*)BpAF;
  const half8* BpB = (const half8*)BpBF;
  const half8* Bpb = (const half8*)BpbF;
  const half8* Bpc = (const half8*)BpcF;

  pack_all_kernel<<<1892, 256, 0, stream>>>(fWa, fWb, fWc, W2a, W2b,
                                            (_Float16*)Bp1F, (_Float16*)BpAF,
                                            (_Float16*)BpBF, (_Float16*)BpbF,
                                            (_Float16*)BpcF);
  down_all_kernel<<<672, 256, 0, stream>>>(x, s1, s2, s3);

  // group 1 (scales 1,2,3) first, then group 0 (the two 512s); h2 buffer reused
  conv12_ms_kernel<1><<<672, 256, 0, stream>>>(x, g, s1, s2, s3, Bp1, fba, Bpb, fbb, h2);
  conv3sd_ms_kernel<1><<<672, 256, 0, stream>>>(h2, Bpc, fbc, x, g, s1, s2, s3, cat);
  conv12_ms_kernel<0><<<4096, 256, 0, stream>>>(x, g, s1, s2, s3, Bp1, fba, Bpb, fbb, h2);
  conv3sd_ms_kernel<0><<<4096, 256, 0, stream>>>(h2, Bpc, fbc, x, g, s1, s2, s3, cat);
  tail_fused_kernel<<<dim3(32, 32, 2), 256, 0, stream>>>(cat, BpA, b2a, BpB, b2b, out);
}

// Round 7
// 538.388 us; speedup vs baseline: 9.4073x; 1.1401x over previous
//
#include <hip/hip_runtime.h>
#include <math.h>

typedef _Float16 half8 __attribute__((ext_vector_type(8)));
typedef float f32x4 __attribute__((ext_vector_type(4)));

// ---------------- merged weight-pack kernel (all 5 packs, r2-verified layouts) -------------
__device__ __forceinline__ void pack_generic(int rem, int NT, int COUT,
                                             const float* __restrict__ src,
                                             _Float16* __restrict__ dst) {
  int j = rem & 7, lane = (rem >> 3) & 63, rest = rem >> 9;
  int t = rest % NT, s = rest / NT;
  int oc = t * 16 + (lane & 15);
  int tap = s >> 1;
  int ic = (s & 1) * 32 + ((lane >> 4) & 3) * 8 + j;
  float v = (oc < COUT) ? src[((size_t)oc * 64 + ic) * 9 + tap] : 0.f;
  dst[rem] = (_Float16)v;
}

__global__ void pack_all_kernel(const float* __restrict__ fWa, const float* __restrict__ fWb,
                                const float* __restrict__ fWc, const float* __restrict__ W2a,
                                const float* __restrict__ W2b,
                                _Float16* __restrict__ Bp1, _Float16* __restrict__ BpA,
                                _Float16* __restrict__ BpB, _Float16* __restrict__ Bpb,
                                _Float16* __restrict__ Bpc) {
  int idx = blockIdx.x * blockDim.x + threadIdx.x;
  if (idx < 184320) {                       // Bpb: 5 scales x 18x4x512
    int sc = idx / 36864, rem = idx - sc * 36864;
    pack_generic(rem, 4, 64, fWb + sc * 36864, Bpb + sc * 36864);
  } else if (idx < 460800) {                // Bpc: 5 scales x 18x6x512
    int i2 = idx - 184320;
    int sc = i2 / 55296, rem = i2 - sc * 55296;
    pack_generic(rem, 6, 81, fWc + sc * 46656, Bpc + sc * 55296);
  } else if (idx < 471040) {                // Bp1: conv1, K=9 pad 32
    int i2 = idx - 460800;
    int sc = i2 >> 11, rem = i2 & 2047;
    int j = rem & 7, lane = (rem >> 3) & 63, nt = rem >> 9;
    int oc = nt * 16 + (lane & 15);
    int k = ((lane >> 4) & 3) * 8 + j;
    float v = (k < 9) ? fWa[sc * 576 + oc * 9 + k] : 0.f;
    Bp1[sc * 2048 + rem] = (_Float16)v;
  } else if (idx < 475136) {                // BpA: tail stage1, K=45 pad 64
    int rem = idx - 471040;
    int j = rem & 7, lane = (rem >> 3) & 63;
    int nt = (rem >> 9) & 3, s = rem >> 11;
    int oc = nt * 16 + (lane & 15);
    int k = s * 32 + ((lane >> 4) & 3) * 8 + j;
    float v = 0.f;
    if (k < 45) { int ic = k / 9, tap = k - ic * 9; v = W2a[(oc * 5 + ic) * 9 + tap]; }
    BpA[rem] = (_Float16)v;
  } else if (idx < 484352) {                // BpB: tail stage2 (COUT=1, NT=1)
    pack_generic(idx - 475136, 1, 1, W2b, BpB);
  }
}

// ---------------- merged nearest downsample (s1,s2,s3 both batches) ----------------
__global__ void down_all_kernel(const float* __restrict__ x, float* __restrict__ s1,
                                float* __restrict__ s2, float* __restrict__ s3) {
  int idx = blockIdx.x * blockDim.x + threadIdx.x;
  if (idx < 131072) {
    int n = idx >> 16, p = idx & 65535, rr = p >> 8, cc = p & 255;
    s1[idx] = x[(size_t)n * 262144 + (size_t)(rr * 2) * 512 + cc * 2];
  } else if (idx < 163840) {
    int i2 = idx - 131072;
    int n = i2 >> 14, p = i2 & 16383, rr = p >> 7, cc = p & 127;
    s2[i2] = x[(size_t)n * 262144 + (size_t)(rr * 4) * 512 + cc * 4];
  } else if (idx < 172032) {
    int i2 = idx - 163840;
    int n = i2 >> 12, p = i2 & 4095, rr = p >> 6, cc = p & 63;
    s3[i2] = x[(size_t)n * 262144 + (size_t)(rr * 8) * 512 + cc * 8];
  }
}

// ---------------- block -> (scale, batch, tile) mapping, compile-time groups --------------
// GROUP 0: scales {0 (x,512), 4 (g,512)}; GROUP 1: {1 (256), 2 (128), 3 (64)}
template <int GROUP>
__device__ __forceinline__ void map_block(int bid, int& sc, int& n, int& bx, int& by,
                                          int& Hs, int& RS, int& h2off) {
  if (GROUP == 0) {
    if (bid < 2048) { sc = 0; Hs = 512; RS = 1; h2off = 0;
      int t = bid; n = t >> 10; t &= 1023; by = t >> 5; bx = t & 31; }
    else { sc = 4; Hs = 512; RS = 1; h2off = 33554432;
      int t = bid - 2048; n = t >> 10; t &= 1023; by = t >> 5; bx = t & 31; }
  } else {
    if (bid < 512) { sc = 1; Hs = 256; RS = 2; h2off = 0;
      int t = bid; n = t >> 8; t &= 255; by = t >> 4; bx = t & 15; }
    else if (bid < 640) { sc = 2; Hs = 128; RS = 4; h2off = 8388608;
      int t = bid - 512; n = t >> 6; t &= 63; by = t >> 3; bx = t & 7; }
    else { sc = 3; Hs = 64; RS = 8; h2off = 10485760;
      int t = bid - 640; n = t >> 4; t &= 15; by = t >> 2; bx = t & 3; }
  }
}

__device__ __forceinline__ const float* pick_src(int sc, const float* x, const float* g,
                                                 const float* s1, const float* s2,
                                                 const float* s3, int& sStr) {
  if (sc == 0) { sStr = 262144; return x; }
  if (sc == 1) { sStr = 65536; return s1; }
  if (sc == 2) { sStr = 16384; return s2; }
  if (sc == 3) { sStr = 4096; return s3; }
  sStr = 262144; return g;
}

// ---------------- shared MFMA K-loop over 18x18x64 swizzled slab (r2-verified) -------------
template <int NT>
__device__ __forceinline__ void mfma_acc18(const _Float16* slab, const half8* __restrict__ Bp,
                                           f32x4 (&acc)[4][NT], int tid) {
  const int lane = tid & 63;
  const int wv = tid >> 6;
  const int quad = lane >> 4;
  const int ln15 = lane & 15;
  const f32x4 zz = {0.f, 0.f, 0.f, 0.f};
#pragma unroll
  for (int mt = 0; mt < 4; ++mt)
#pragma unroll
    for (int nt = 0; nt < NT; ++nt) acc[mt][nt] = zz;
#pragma unroll 1
  for (int s = 0; s < 18; ++s) {
    const int tap = s >> 1;
    const int dy = tap / 3;
    const int dx = tap - dy * 3;
    half8 bf[NT];
#pragma unroll
    for (int nt = 0; nt < NT; ++nt) bf[nt] = Bp[(s * NT + nt) * 64 + lane];
    const int C = dx + ln15;
    const int qsw = (((s & 1) * 4 + quad) ^ (C & 7));
    const _Float16* base = slab + C * 64 + qsw * 8;
    half8 af[4];
#pragma unroll
    for (int mt = 0; mt < 4; ++mt) {
      const int R = wv * 4 + mt + dy;
      af[mt] = *(const half8*)(base + R * (18 * 64));
    }
#pragma unroll
    for (int mt = 0; mt < 4; ++mt)
#pragma unroll
      for (int nt = 0; nt < NT; ++nt)
        acc[mt][nt] = __builtin_amdgcn_mfma_f32_16x16x32_f16(af[mt], bf[nt], acc[mt][nt], 0, 0, 0);
  }
}

template <int NT, int COUT, int COUTP, bool RELU, typename OutT>
__device__ __forceinline__ void mfma_body(const _Float16* slab, const half8* __restrict__ Bp,
                                          const float* __restrict__ bias,
                                          OutT* __restrict__ out,
                                          int H, int W, int gr0, int gc0, int tid) {
  f32x4 acc[4][NT];
  mfma_acc18<NT>(slab, Bp, acc, tid);
  const int lane = tid & 63;
  const int wv = tid >> 6;
  const int quad = lane >> 4;
  const int ln15 = lane & 15;
#pragma unroll
  for (int nt = 0; nt < NT; ++nt) {
    const int oc = nt * 16 + ln15;
    const float bv = (oc < COUT) ? bias[oc] : 0.f;
#pragma unroll
    for (int mt = 0; mt < 4; ++mt) {
      const int gr = gr0 + wv * 4 + mt;
#pragma unroll
      for (int reg = 0; reg < 4; ++reg) {
        const int gc = gc0 + quad * 4 + reg;
        float v = acc[mt][nt][reg] + bv;
        if (RELU) v = fmaxf(v, 0.f);
        if (oc < COUTP) out[((size_t)gr * W + gc) * COUTP + oc] = (OutT)v;
      }
    }
  }
}

// ---------------- multi-scale fused conv1+conv2 (MFMA), one dispatch per group ------------
template <int GROUP>
__global__ __launch_bounds__(256)
void conv12_ms_kernel(const float* __restrict__ x, const float* __restrict__ g,
                      const float* __restrict__ s1, const float* __restrict__ s2,
                      const float* __restrict__ s3,
                      const half8* __restrict__ Bp1b, const float* __restrict__ fba,
                      const half8* __restrict__ Bpbb, const float* __restrict__ fbb,
                      _Float16* __restrict__ h2) {
  __shared__ float xs[20 * 20];                         // first: gather clamps stay inside
  __shared__ __align__(16) _Float16 slab[18 * 18 * 64];
  int sc, n, bx, by, Hs, RS, h2off;
  map_block<GROUP>(blockIdx.x, sc, n, bx, by, Hs, RS, h2off);
  int sStr;
  const float* src = pick_src(sc, x, g, s1, s2, s3, sStr);
  const float* in = src + (size_t)n * sStr;
  _Float16* out = h2 + h2off + (size_t)n * Hs * Hs * 64;
  const half8* Bp1 = Bp1b + sc * 256;
  const half8* Bp = Bpbb + sc * 4608;
  const float* ba = fba + sc * 64;
  const float* bb = fbb + sc * 64;
  const int H = Hs, W = Hs;
  const int tid = threadIdx.x;
  const int gr0 = by * 16, gc0 = bx * 16;
  for (int i = tid; i < 400; i += 256) {
    int R = i / 20, C = i % 20;
    int gr = gr0 - 2 + R, gc = gc0 - 2 + C;
    xs[i] = (gr >= 0 && gr < H && gc >= 0 && gc < W) ? in[(size_t)gr * W + gc] : 0.f;
  }
  __syncthreads();
  const int lane = tid & 63;
  const int wv = tid >> 6;
  const int quad = lane >> 4;
  const int ln15 = lane & 15;
  half8 bf1[4];
  float bv1[4];
#pragma unroll
  for (int nt = 0; nt < 4; ++nt) {
    bf1[nt] = Bp1[nt * 64 + lane];
    bv1[nt] = ba[nt * 16 + ln15];
  }
  int off1[8];
  bool v1[8];
#pragma unroll
  for (int j = 0; j < 8; ++j) {
    int k = quad * 8 + j;
    v1[j] = (k < 9);
    off1[j] = v1[j] ? ((k / 3) * 20 + (k % 3)) : 0;
  }
  const f32x4 zz = {0.f, 0.f, 0.f, 0.f};
#pragma unroll 1
  for (int mt = wv; mt < 21; mt += 4) {
    int p = mt * 16 + ln15;
    int pcl = (p < 323) ? p : 323;
    int R = pcl / 18, C = pcl - R * 18;
    int base = R * 20 + C;
    half8 af;
#pragma unroll
    for (int j = 0; j < 8; ++j)
      af[j] = v1[j] ? (_Float16)xs[base + off1[j]] : (_Float16)0.f;
    f32x4 a1[4] = {zz, zz, zz, zz};
#pragma unroll
    for (int nt = 0; nt < 4; ++nt)
      a1[nt] = __builtin_amdgcn_mfma_f32_16x16x32_f16(af, bf1[nt], a1[nt], 0, 0, 0);
#pragma unroll
    for (int nt = 0; nt < 4; ++nt) {
      const int oc = nt * 16 + ln15;
#pragma unroll
      for (int reg = 0; reg < 4; ++reg) {
        int p2 = mt * 16 + quad * 4 + reg;
        if (p2 < 324) {
          int R2 = p2 / 18, C2 = p2 - R2 * 18;
          int gr = gr0 - 1 + R2, gc = gc0 - 1 + C2;
          float v = (gr >= 0 && gr < H && gc >= 0 && gc < W)
                        ? fmaxf(a1[nt][reg] + bv1[nt], 0.f) : 0.f;
          slab[p2 * 64 + (((oc >> 3) ^ (C2 & 7)) * 8) + (oc & 7)] = (_Float16)v;
        }
      }
    }
  }
  __syncthreads();
  mfma_body<4, 64, 64, true, _Float16>(slab, Bp, bb, out, H, W, gr0, gc0, tid);
}

// ---------------- multi-scale fused conv3 + softmax + dynconv + upsample ------------------
// Epilogue: r5-proven butterfly. Pixel (row=wv*4+mt, col=quad*4+reg) has its 96 channels
// in the 16 lanes of its quad-group (ch = nt*16+ln15): 6 masked exp + xs gather per lane,
// then 4-step width-16 shfl_xor reduction; lane ln15==0 writes oarr.
template <int GROUP>
__global__ __launch_bounds__(256)
void conv3sd_ms_kernel(const _Float16* __restrict__ h2, const half8* __restrict__ Bpcb,
                       const float* __restrict__ fbc,
                       const float* __restrict__ x, const float* __restrict__ g,
                       const float* __restrict__ s1, const float* __restrict__ s2,
                       const float* __restrict__ s3, float* __restrict__ cat) {
  __shared__ __align__(16) _Float16 slab[18 * 18 * 64];
  __shared__ float xs[24 * 24];
  __shared__ float oarr[256];
  int sc, n, bx, by, Hs, RS, h2off;
  map_block<GROUP>(blockIdx.x, sc, n, bx, by, Hs, RS, h2off);
  int sStr;
  const float* src = pick_src(sc, x, g, s1, s2, s3, sStr);
  const float* s = src + (size_t)n * sStr;
  const _Float16* in = h2 + h2off + (size_t)n * Hs * Hs * 64;
  const half8* Bp = Bpcb + sc * 6912;
  const float* bias = fbc + sc * 81;
  float* catn = cat + (size_t)n * 1310720;
  const int H = Hs, W = Hs;
  const int tid = threadIdx.x;
  const int gr0 = by * 16, gc0 = bx * 16;
  for (int i = tid; i < 18 * 18 * 8; i += 256) {
    int chunk = i & 7, px = i >> 3;
    int R = px / 18, C = px % 18;
    int gr = gr0 - 1 + R, gc = gc0 - 1 + C;
    half8 v = {0, 0, 0, 0, 0, 0, 0, 0};
    if (gr >= 0 && gr < H && gc >= 0 && gc < W)
      v = *(const half8*)(in + ((size_t)gr * W + gc) * 64 + chunk * 8);
    *(half8*)(slab + px * 64 + (chunk ^ (C & 7)) * 8) = v;
  }
  for (int i = tid; i < 576; i += 256) {
    int R = i / 24, C = i % 24;
    int gr = gr0 - 4 + R, gc = gc0 - 4 + C;
    xs[i] = (gr >= 0 && gr < H && gc >= 0 && gc < W) ? s[(size_t)gr * W + gc] : 0.f;
  }
  __syncthreads();
  f32x4 acc[4][6];
  mfma_acc18<6>(slab, Bp, acc, tid);
  const int lane = tid & 63;
  const int wv = tid >> 6;
  const int quad = lane >> 4;
  const int ln15 = lane & 15;
  float bv[6];
  int dyx[6];
  bool val[6];
#pragma unroll
  for (int nt = 0; nt < 6; ++nt) {
    int ch = nt * 16 + ln15;
    val[nt] = (ch < 81);
    bv[nt] = val[nt] ? bias[ch] : 0.f;
    int dy = ch / 9, dx = ch - dy * 9;
    dyx[nt] = val[nt] ? dy * 24 + dx : 0;
  }
#pragma unroll
  for (int mt = 0; mt < 4; ++mt) {
    const int pr = wv * 4 + mt;
#pragma unroll
    for (int reg = 0; reg < 4; ++reg) {
      const int pc = quad * 4 + reg;
      const int base = pr * 24 + pc;
      float sum = 0.f, y = 0.f;
#pragma unroll
      for (int nt = 0; nt < 6; ++nt) {
        float e = val[nt] ? __expf(acc[mt][nt][reg] + bv[nt]) : 0.f;
        sum += e;
        y = fmaf(e, xs[base + dyx[nt]], y);
      }
#pragma unroll
      for (int m = 1; m < 16; m <<= 1) {
        sum += __shfl_xor(sum, m, 64);
        y   += __shfl_xor(y, m, 64);
      }
      if (ln15 == 0) oarr[pr * 16 + pc] = y / sum;
    }
  }
  __syncthreads();
  const int px = tid;
  const float o = oarr[px];
  const int gr = gr0 + (px >> 4), gc = gc0 + (px & 15);
  for (int a = 0; a < RS; ++a)
    for (int b = 0; b < RS; ++b)
      catn[((size_t)(gr * RS + a) * 512 + (gc * RS + b)) * 5 + sc] = o;
}

// ---------------- fused tail: cat(5) -> MFMA 5->64 relu (LDS) -> MFMA 64->1 ----------------
__global__ __launch_bounds__(256)
void tail_fused_kernel(const float* __restrict__ cat,
                       const half8* __restrict__ BpA, const float* __restrict__ b2a,
                       const half8* __restrict__ BpB, const float* __restrict__ b2b,
                       float* __restrict__ out) {
  __shared__ float cs[20 * 20 * 5];                      // first: gather clamps stay inside
  __shared__ __align__(16) _Float16 hid[18 * 18 * 64];
  const int n = blockIdx.z;
  const float* cin = cat + (size_t)n * (512 * 512 * 5);
  float* op = out + (size_t)n * (512 * 512);
  const int tid = threadIdx.x;
  const int gr0 = blockIdx.y * 16, gc0 = blockIdx.x * 16;
  for (int i = tid; i < 2000; i += 256) {
    int px = i / 5, ic = i - px * 5;
    int R = px / 20, C = px - R * 20;
    int gr = gr0 - 2 + R, gc = gc0 - 2 + C;
    cs[i] = (gr >= 0 && gr < 512 && gc >= 0 && gc < 512)
                ? cin[((size_t)gr * 512 + gc) * 5 + ic] : 0.f;
  }
  __syncthreads();
  const int lane = tid & 63;
  const int wv = tid >> 6;
  const int quad = lane >> 4;
  const int ln15 = lane & 15;
  int goff[2][8];
  bool gok[2][8];
#pragma unroll
  for (int s = 0; s < 2; ++s)
#pragma unroll
    for (int j = 0; j < 8; ++j) {
      int k = s * 32 + quad * 8 + j;
      bool ok = (k < 45);
      int ic = k / 9;
      int tap = k - ic * 9;
      int dy = tap / 3, dx = tap - dy * 3;
      goff[s][j] = ok ? ((dy * 20 + dx) * 5 + ic) : 0;
      gok[s][j] = ok;
    }
  half8 bfA[2][4];
#pragma unroll
  for (int s = 0; s < 2; ++s)
#pragma unroll
    for (int nt = 0; nt < 4; ++nt) bfA[s][nt] = BpA[(s * 4 + nt) * 64 + lane];
  float bvA[4];
#pragma unroll
  for (int nt = 0; nt < 4; ++nt) bvA[nt] = b2a[nt * 16 + ln15];
  const f32x4 zz = {0.f, 0.f, 0.f, 0.f};
#pragma unroll 1
  for (int mt = wv; mt < 21; mt += 4) {
    int px = mt * 16 + ln15;
    int pc = (px < 323) ? px : 323;
    int base = (pc / 18) * 100 + (pc % 18) * 5;
    f32x4 acc1[4] = {zz, zz, zz, zz};
#pragma unroll
    for (int s = 0; s < 2; ++s) {
      half8 af;
#pragma unroll
      for (int j = 0; j < 8; ++j) {
        float a = gok[s][j] ? cs[base + goff[s][j]] : 0.f;
        af[j] = (_Float16)a;
      }
#pragma unroll
      for (int nt = 0; nt < 4; ++nt)
        acc1[nt] = __builtin_amdgcn_mfma_f32_16x16x32_f16(af, bfA[s][nt], acc1[nt], 0, 0, 0);
    }
#pragma unroll
    for (int nt = 0; nt < 4; ++nt) {
      const int oc = nt * 16 + ln15;
#pragma unroll
      for (int reg = 0; reg < 4; ++reg) {
        int p2 = mt * 16 + quad * 4 + reg;
        if (p2 < 324) {
          int R = p2 / 18, C = p2 - R * 18;
          int gr = gr0 - 1 + R, gc = gc0 - 1 + C;
          float v = (gr >= 0 && gr < 512 && gc >= 0 && gc < 512)
                        ? fmaxf(acc1[nt][reg] + bvA[nt], 0.f) : 0.f;
          hid[p2 * 64 + (((oc >> 3) ^ (C & 7)) * 8) + (oc & 7)] = (_Float16)v;
        }
      }
    }
  }
  __syncthreads();
  mfma_body<1, 1, 1, false, float>(hid, BpB, b2b, op, 512, 512, gr0, gc0, tid);
}

extern "C" void kernel_launch(void* const* d_in, const int* in_sizes, int n_in,
                              void* d_out, int out_size, void* d_ws, size_t ws_size,
                              hipStream_t stream) {
  (void)in_sizes; (void)n_in; (void)out_size; (void)ws_size;
  const float* x   = (const float*)d_in[0];
  const float* g   = (const float*)d_in[1];
  const float* fWa = (const float*)d_in[2];
  const float* fba = (const float*)d_in[3];
  const float* fWb = (const float*)d_in[4];
  const float* fbb = (const float*)d_in[5];
  const float* fWc = (const float*)d_in[6];
  const float* fbc = (const float*)d_in[7];
  const float* W2a = (const float*)d_in[8];
  const float* b2a = (const float*)d_in[9];
  const float* W2b = (const float*)d_in[10];
  const float* b2b = (const float*)d_in[11];
  float* out = (float*)d_out;
  float* ws = (float*)d_ws;

  // carve (float units), total ~36.6M floats = 146 MB
  float* Bp1F = ws;                     // 10240 halves = 5120 floats
  float* BpAF = Bp1F + 5120;            // 2048
  float* BpBF = BpAF + 2048;            // 4608
  float* BpbF = BpBF + 4608;            // 92160
  float* BpcF = BpbF + 92160;           // 138240
  float* s1   = BpcF + 138240;          // 131072
  float* s2   = s1 + 131072;            // 32768
  float* s3   = s2 + 32768;             // 8192
  float* cat  = s3 + 8192;              // 2621440
  float* h2F  = cat + 2621440;          // 67108864 halves = 33554432 floats
  _Float16* h2 = (_Float16*)h2F;
  const half8* Bp1 = (const half8*)Bp1F;
  const half8* BpA = (const half8*)BpAF;
  const half8* BpB = (const half8*)BpBF;
  const half8* Bpb = (const half8*)BpbF;
  const half8* Bpc = (const half8*)BpcF;

  pack_all_kernel<<<1892, 256, 0, stream>>>(fWa, fWb, fWc, W2a, W2b,
                                            (_Float16*)Bp1F, (_Float16*)BpAF,
                                            (_Float16*)BpBF, (_Float16*)BpbF,
                                            (_Float16*)BpcF);
  down_all_kernel<<<672, 256, 0, stream>>>(x, s1, s2, s3);

  // group 1 (scales 1,2,3) first, then group 0 (the two 512s); h2 buffer reused
  conv12_ms_kernel<1><<<672, 256, 0, stream>>>(x, g, s1, s2, s3, Bp1, fba, Bpb, fbb, h2);
  conv3sd_ms_kernel<1><<<672, 256, 0, stream>>>(h2, Bpc, fbc, x, g, s1, s2, s3, cat);
  conv12_ms_kernel<0><<<4096, 256, 0, stream>>>(x, g, s1, s2, s3, Bp1, fba, Bpb, fbb, h2);
  conv3sd_ms_kernel<0><<<4096, 256, 0, stream>>>(h2, Bpc, fbc, x, g, s1, s2, s3, cat);
  tail_fused_kernel<<<dim3(32, 32, 2), 256, 0, stream>>>(cat, BpA, b2a, BpB, b2b, out);
}